// Round 4
// baseline (223.852 us; speedup 1.0000x reference)
//
#include <hip/hip_runtime.h>

typedef unsigned short u16;
typedef unsigned u32;
typedef u16 u16x8 __attribute__((ext_vector_type(8)));
typedef u16 u16x4 __attribute__((ext_vector_type(4)));
typedef u32 u32x4 __attribute__((ext_vector_type(4)));
typedef __bf16 bf8 __attribute__((ext_vector_type(8)));
typedef float f32x4 __attribute__((ext_vector_type(4)));
typedef float f32x16 __attribute__((ext_vector_type(16)));

__device__ __forceinline__ u16 f2b(float f) {
  unsigned u = __float_as_uint(f);
  u += 0x7FFFu + ((u >> 16) & 1u);   // RNE
  return (u16)(u >> 16);
}
__device__ __forceinline__ float b2f(u16 h) {
  return __uint_as_float(((unsigned)h) << 16);
}
__device__ __forceinline__ bf8 asbf8(u16x8 v) {
  return __builtin_bit_cast(bf8, v);
}
__device__ __forceinline__ void gll16(const u16* g, u16* l) {
  __builtin_amdgcn_global_load_lds(
      (const __attribute__((address_space(1))) unsigned*)(g),
      (__attribute__((address_space(3))) unsigned*)(l), 16, 0, 0);
}
__device__ __forceinline__ u32 cvtpk(float lo, float hi) {
  u32 r;
  asm("v_cvt_pk_bf16_f32 %0, %1, %2" : "=v"(r) : "v"(lo), "v"(hi));
  return r;
}
// v_permlane32_swap_b32 a, b:  a.hi32lanes <-> b.lo32lanes
// => a' = {lo: a.lo, hi: b.lo},  b' = {lo: a.hi, hi: b.hi}
__device__ __forceinline__ void plswap(u32& a, u32& b) {
  asm("v_permlane32_swap_b32 %0, %1" : "+v"(a), "+v"(b));
}

// ---------------- prep kernels ----------------

__global__ __launch_bounds__(256) void xconv(const float* __restrict__ x,
                                             u16* __restrict__ xb) {
  int i = (blockIdx.x * 256 + threadIdx.x) * 4;
  float4 v = *(const float4*)(x + i);
  u16x4 o;
  o[0] = f2b(v.x); o[1] = f2b(v.y); o[2] = f2b(v.z); o[3] = f2b(v.w);
  *(u16x4*)(xb + i) = o;
}

// in [K][N] f32  ->  out [N][K] bf16   (transpose + convert)
__global__ __launch_bounds__(256) void wtrans(const float* __restrict__ in,
                                              u16* __restrict__ out,
                                              int N, int K) {
  __shared__ float tile[32][33];
  int tx = threadIdx.x & 31, ty = threadIdx.x >> 5;
  int n0 = blockIdx.x * 32, k0 = blockIdx.y * 32;
#pragma unroll
  for (int yy = 0; yy < 32; yy += 8)
    tile[ty + yy][tx] = in[(size_t)(k0 + ty + yy) * N + n0 + tx];
  __syncthreads();
#pragma unroll
  for (int yy = 0; yy < 32; yy += 8)
    out[(size_t)(n0 + ty + yy) * K + k0 + tx] = f2b(tile[tx][ty + yy]);
}

// RoPE in-place on q (cols 0..2047) and k (cols 2048..2559) of qkv [2048][3072]
__global__ __launch_bounds__(256) void rope_k(u16* __restrict__ qkv,
                                              const float* __restrict__ cs,
                                              const float* __restrict__ sn) {
  int idx = blockIdx.x * 256 + threadIdx.x;  // 2048*40*32
  int dp = idx & 31;
  int hh = (idx >> 5) % 40;
  int s  = idx / 1280;
  int col = (hh < 32) ? (hh * 64 + dp) : (2048 + (hh - 32) * 64 + dp);
  u16* p = qkv + (size_t)s * 3072 + col;
  float v1 = b2f(p[0]), v2 = b2f(p[32]);
  float c1 = cs[s * 64 + dp],      s1 = sn[s * 64 + dp];
  float c2 = cs[s * 64 + dp + 32], s2 = sn[s * 64 + dp + 32];
  p[0]  = f2b(v1 * c1 - v2 * s1);
  p[32] = f2b(v2 * c2 + v1 * s2);
}

// Vt[kh][d][s] = qkv[s][2560 + kh*64 + d]
__global__ __launch_bounds__(256) void vtrans(const u16* __restrict__ qkv,
                                              u16* __restrict__ Vt) {
  int idx = blockIdx.x * 256 + threadIdx.x;  // 8*64*2048 = 1<<20
  int s  = idx & 2047;
  int d  = (idx >> 11) & 63;
  int kh = idx >> 17;
  Vt[idx] = qkv[(size_t)s * 3072 + 2560 + kh * 64 + d];
}

// ---------------- GEMM: C[M][N] = A[M][K] * Bt[N][K]^T ----------------

__global__ __launch_bounds__(256) void gemm_bt(const u16* __restrict__ A,
                                               const u16* __restrict__ Bt,
                                               void* __restrict__ Cout,
                                               int M, int N, int K, int obf16) {
  __shared__ __align__(16) u16 As[128 * 32];
  __shared__ __align__(16) u16 Bs[128 * 32];
  const int t = threadIdx.x;
  const int lane = t & 63, wid = t >> 6;
  const int wm = (wid >> 1) * 64, wn = (wid & 1) * 64;
  const int la = lane & 15, lg = lane >> 4;
  const int m0 = blockIdx.y * 128, n0 = blockIdx.x * 128;

  const int c0 = wid * 2;
  const int srow = c0 * 16 + (lane >> 2);
  const int scol = (lane & 3) * 8;
  const u16* Ap = A + (size_t)(m0 + srow) * K + scol;
  const u16* Bp = Bt + (size_t)(n0 + srow) * K + scol;
  u16* Ad0 = &As[c0 * 512];
  u16* Ad1 = &As[(c0 + 1) * 512];
  u16* Bd0 = &Bs[c0 * 512];
  u16* Bd1 = &Bs[(c0 + 1) * 512];
  const size_t rstepA = (size_t)16 * K;

  f32x4 acc[4][4] = {};

  for (int k0 = 0; k0 < K; k0 += 32) {
    __syncthreads();
    gll16(Ap + k0, Ad0);
    gll16(Ap + k0 + rstepA, Ad1);
    gll16(Bp + k0, Bd0);
    gll16(Bp + k0 + rstepA, Bd1);
    __syncthreads();
    bf8 af[4], bfr[4];
#pragma unroll
    for (int i = 0; i < 4; ++i)
      af[i] = asbf8(*(const u16x8*)(&As[(wm + i * 16 + la) * 32 + lg * 8]));
#pragma unroll
    for (int j = 0; j < 4; ++j)
      bfr[j] = asbf8(*(const u16x8*)(&Bs[(wn + j * 16 + la) * 32 + lg * 8]));
    __builtin_amdgcn_s_setprio(1);
#pragma unroll
    for (int i = 0; i < 4; ++i)
#pragma unroll
      for (int j = 0; j < 4; ++j)
        acc[i][j] = __builtin_amdgcn_mfma_f32_16x16x32_bf16(af[i], bfr[j],
                                                            acc[i][j], 0, 0, 0);
    __builtin_amdgcn_s_setprio(0);
  }

#pragma unroll
  for (int i = 0; i < 4; ++i)
#pragma unroll
    for (int j = 0; j < 4; ++j)
#pragma unroll
      for (int r = 0; r < 4; ++r) {
        int row = m0 + wm + i * 16 + lg * 4 + r;
        int col = n0 + wn + j * 16 + la;
        if (obf16) ((u16*)Cout)[(size_t)row * N + col] = f2b(acc[i][j][r]);
        else       ((float*)Cout)[(size_t)row * N + col] = acc[i][j][r];
      }
}

// ---------------- flash attention: swapped-QK 32x32, 1 wave / 32 q-rows ----
// S^T = mfma(K, Q): lane holds col q = lane&31; kv rows split across lane
// halves (crow = (r&3)+8*(r>>2)+4*hi). Softmax fully in-register (base-2).
// P -> PV A-frags via cvt_pk + permlane32_swap (T12). No LDS, no barriers.

#define LOADKV(K0,K1,K2,K3,V0,V1,V2,V3,b) do {                       \
    const u16* kp_ = kbase + (size_t)(b) * 98304;                    \
    K0 = asbf8(*(const u16x8*)(kp_));                                \
    K1 = asbf8(*(const u16x8*)(kp_ + 16));                           \
    K2 = asbf8(*(const u16x8*)(kp_ + 32));                           \
    K3 = asbf8(*(const u16x8*)(kp_ + 48));                           \
    const u16* vp_ = vbase + (b) * 32;                               \
    V0 = asbf8(*(const u16x8*)(vp_));                                \
    V1 = asbf8(*(const u16x8*)(vp_ + 16));                           \
    V2 = asbf8(*(const u16x8*)(vp_ + 65536));                        \
    V3 = asbf8(*(const u16x8*)(vp_ + 65536 + 16));                   \
  } while (0)

#define STEP(K0,K1,K2,K3,V0,V1,V2,V3,b) do {                         \
    f32x16 s = {};                                                   \
    __builtin_amdgcn_s_setprio(1);                                   \
    s = __builtin_amdgcn_mfma_f32_32x32x16_bf16(K0, qf0, s, 0, 0, 0);\
    s = __builtin_amdgcn_mfma_f32_32x32x16_bf16(K1, qf1, s, 0, 0, 0);\
    s = __builtin_amdgcn_mfma_f32_32x32x16_bf16(K2, qf2, s, 0, 0, 0);\
    s = __builtin_amdgcn_mfma_f32_32x32x16_bf16(K3, qf3, s, 0, 0, 0);\
    __builtin_amdgcn_s_setprio(0);                                   \
    if ((b) == nb - 1) {                                             \
      _Pragma("unroll") for (int r = 0; r < 16; ++r) {               \
        int kvr = (b) * 32 + (r & 3) + 8 * (r >> 2) + 4 * hi;        \
        if (kvr > q0w + la) s[r] = -1e30f;                           \
      }                                                              \
    }                                                                \
    float pmax = s[0];                                               \
    _Pragma("unroll") for (int r = 1; r < 16; ++r)                   \
      pmax = fmaxf(pmax, s[r]);                                      \
    if (!__all(pmax - m_run <= 8.0f)) {                              \
      float om = __shfl_xor(pmax, 32);                               \
      float mn = fmaxf(m_run, fmaxf(pmax, om));                      \
      float sc = exp2f(m_run - mn);                                  \
      m_run = mn; l_run *= sc;                                       \
      _Pragma("unroll") for (int r = 0; r < 16; ++r) {               \
        float scr = __shfl(sc, (r & 3) + 8 * (r >> 2) + 4 * hi);     \
        o0[r] *= scr; o1[r] *= scr;                                  \
      }                                                              \
    }                                                                \
    float ls = 0.f;                                                  \
    _Pragma("unroll") for (int r = 0; r < 16; ++r) {                 \
      s[r] = exp2f(s[r] - m_run); ls += s[r];                        \
    }                                                                \
    l_run += ls;                                                     \
    u32 c0 = cvtpk(s[0], s[1]),   c1 = cvtpk(s[2], s[3]);            \
    u32 c2 = cvtpk(s[4], s[5]),   c3 = cvtpk(s[6], s[7]);            \
    u32 c4 = cvtpk(s[8], s[9]),   c5 = cvtpk(s[10], s[11]);          \
    u32 c6 = cvtpk(s[12], s[13]), c7 = cvtpk(s[14], s[15]);          \
    plswap(c0, c2); plswap(c1, c3); plswap(c4, c6); plswap(c5, c7);  \
    u32x4 t0; t0[0] = c0; t0[1] = c1; t0[2] = c2; t0[3] = c3;        \
    u32x4 t1; t1[0] = c4; t1[1] = c5; t1[2] = c6; t1[3] = c7;        \
    bf8 pa0 = __builtin_bit_cast(bf8, t0);                           \
    bf8 pa1 = __builtin_bit_cast(bf8, t1);                           \
    __builtin_amdgcn_s_setprio(1);                                   \
    o0 = __builtin_amdgcn_mfma_f32_32x32x16_bf16(pa0, V0, o0, 0, 0, 0);\
    o0 = __builtin_amdgcn_mfma_f32_32x32x16_bf16(pa1, V1, o0, 0, 0, 0);\
    o1 = __builtin_amdgcn_mfma_f32_32x32x16_bf16(pa0, V2, o1, 0, 0, 0);\
    o1 = __builtin_amdgcn_mfma_f32_32x32x16_bf16(pa1, V3, o1, 0, 0, 0);\
    __builtin_amdgcn_s_setprio(0);                                   \
  } while (0)

__global__ __launch_bounds__(64) void attn_fwd(const u16* __restrict__ qkv,
                                               const u16* __restrict__ Vt,
                                               u16* __restrict__ aout) {
  const int h  = blockIdx.x;
  const int qt = 63 - (int)blockIdx.y;   // heavy q-tiles dispatch first
  const int nb = qt + 1;                 // 32-kv blocks
  const int q0w = qt * 32;
  const int kh = h >> 2;                 // GROUPS = 4
  const int l = threadIdx.x;
  const int la = l & 31;
  const int hi = l >> 5;

  // Q B-fragments, prescaled by 0.125*log2(e) (base-2 softmax domain)
  bf8 qf0, qf1, qf2, qf3;
  {
    const u16* qp = qkv + (size_t)(q0w + la) * 3072 + h * 64 + hi * 8;
    const float SC = 0.125f * 1.44269504088896340736f;
#define QLOAD(dst, kk) do {                                          \
      u16x8 v = *(const u16x8*)(qp + (kk) * 16);                     \
      u16x8 sv;                                                      \
      _Pragma("unroll") for (int e = 0; e < 8; ++e)                  \
        sv[e] = f2b(b2f(v[e]) * SC);                                 \
      dst = asbf8(sv);                                               \
    } while (0)
    QLOAD(qf0, 0); QLOAD(qf1, 1); QLOAD(qf2, 2); QLOAD(qf3, 3);
#undef QLOAD
  }

  const u16* kbase = qkv + (size_t)la * 3072 + 2048 + kh * 64 + hi * 8;
  const u16* vbase = Vt + ((size_t)kh * 64 + la) * 2048 + hi * 8;

  f32x16 o0 = {}, o1 = {};
  float m_run = -1e30f, l_run = 0.f;

  bf8 kA0, kA1, kA2, kA3, vA0, vA1, vA2, vA3;
  bf8 kB0, kB1, kB2, kB3, vB0, vB1, vB2, vB3;

  LOADKV(kA0, kA1, kA2, kA3, vA0, vA1, vA2, vA3, 0);
  for (int b = 0;;) {
    if (b + 1 < nb) LOADKV(kB0, kB1, kB2, kB3, vB0, vB1, vB2, vB3, b + 1);
    STEP(kA0, kA1, kA2, kA3, vA0, vA1, vA2, vA3, b);
    ++b; if (b >= nb) break;
    if (b + 1 < nb) LOADKV(kA0, kA1, kA2, kA3, vA0, vA1, vA2, vA3, b + 1);
    STEP(kB0, kB1, kB2, kB3, vB0, vB1, vB2, vB3, b);
    ++b; if (b >= nb) break;
  }

  // epilogue: combine half-row sums, normalize, store
  float lt = l_run + __shfl_xor(l_run, 32);
  float linv = 1.0f / lt;
  u16* op = aout + (size_t)q0w * 2048 + h * 64 + la;
#pragma unroll
  for (int r = 0; r < 16; ++r) {
    int crow = (r & 3) + 8 * (r >> 2) + 4 * hi;
    float lr = __shfl(linv, crow);
    op[(size_t)crow * 2048]      = f2b(o0[r] * lr);
    op[(size_t)crow * 2048 + 32] = f2b(o1[r] * lr);
  }
}

// ---------------- launch ----------------

extern "C" void kernel_launch(void* const* d_in, const int* in_sizes, int n_in,
                              void* d_out, int out_size, void* d_ws, size_t ws_size,
                              hipStream_t stream) {
  (void)in_sizes; (void)n_in; (void)out_size; (void)ws_size;
  const float* x  = (const float*)d_in[0];
  const float* wq = (const float*)d_in[1];
  const float* wk = (const float*)d_in[2];
  const float* wv = (const float*)d_in[3];
  const float* wo = (const float*)d_in[4];
  const float* cs = (const float*)d_in[5];
  const float* sn = (const float*)d_in[6];
  // d_in[7] = causal mask, implemented analytically

  u16* ws    = (u16*)d_ws;
  u16* xb    = ws;                               // [2048][2048]  (later reused as aout)
  u16* wqkvT = ws + 4194304;                     // [3072][2048]  (later reused for Vt)
  u16* qkv   = ws + 4194304 + 6291456;           // [2048][3072]
  u16* woT   = ws + 4194304 + 6291456 * 2;       // [2048][2048]
  u16* Vt    = wqkvT;                            // [8][64][2048] after G1 is done
  u16* aout  = xb;                               // after G1 is done

  xconv<<<4096, 256, 0, stream>>>(x, xb);
  wtrans<<<dim3(64, 64), 256, 0, stream>>>(wq, wqkvT, 2048, 2048);
  wtrans<<<dim3(16, 64), 256, 0, stream>>>(wk, wqkvT + (size_t)2048 * 2048, 512, 2048);
  wtrans<<<dim3(16, 64), 256, 0, stream>>>(wv, wqkvT + (size_t)2560 * 2048, 512, 2048);
  wtrans<<<dim3(64, 64), 256, 0, stream>>>(wo, woT, 2048, 2048);

  gemm_bt<<<dim3(24, 16), 256, 0, stream>>>(xb, wqkvT, qkv, 2048, 3072, 2048, 1);
  rope_k<<<10240, 256, 0, stream>>>(qkv, cs, sn);
  vtrans<<<4096, 256, 0, stream>>>(qkv, Vt);
  attn_fwd<<<dim3(32, 64), 64, 0, stream>>>(qkv, Vt, aout);
  gemm_bt<<<dim3(16, 16), 256, 0, stream>>>(aout, woT, d_out, 2048, 2048, 2048, 0);
}

// Round 5
// 217.624 us; speedup vs baseline: 1.0286x; 1.0286x over previous
//
#include <hip/hip_runtime.h>

typedef unsigned short u16;
typedef unsigned u32;
typedef u16 u16x8 __attribute__((ext_vector_type(8)));
typedef u16 u16x4 __attribute__((ext_vector_type(4)));
typedef u32 u32x4 __attribute__((ext_vector_type(4)));
typedef __bf16 bf8 __attribute__((ext_vector_type(8)));
typedef float f32x4 __attribute__((ext_vector_type(4)));
typedef float f32x16 __attribute__((ext_vector_type(16)));

__device__ __forceinline__ u16 f2b(float f) {
  unsigned u = __float_as_uint(f);
  u += 0x7FFFu + ((u >> 16) & 1u);   // RNE
  return (u16)(u >> 16);
}
__device__ __forceinline__ float b2f(u16 h) {
  return __uint_as_float(((unsigned)h) << 16);
}
__device__ __forceinline__ bf8 asbf8(u16x8 v) {
  return __builtin_bit_cast(bf8, v);
}
__device__ __forceinline__ void gll16(const u16* g, u16* l) {
  __builtin_amdgcn_global_load_lds(
      (const __attribute__((address_space(1))) unsigned*)(g),
      (__attribute__((address_space(3))) unsigned*)(l), 16, 0, 0);
}
__device__ __forceinline__ u32 cvtpk(float lo, float hi) {
  u32 r;
  asm("v_cvt_pk_bf16_f32 %0, %1, %2" : "=v"(r) : "v"(lo), "v"(hi));
  return r;
}
// v_permlane32_swap_b32 a, b:  a.hi32lanes <-> b.lo32lanes
// => a' = {lo: a.lo, hi: b.lo},  b' = {lo: a.hi, hi: b.hi}
__device__ __forceinline__ void plswap(u32& a, u32& b) {
  asm("v_permlane32_swap_b32 %0, %1" : "+v"(a), "+v"(b));
}

// ---------------- prep kernels ----------------

__global__ __launch_bounds__(256) void xconv(const float* __restrict__ x,
                                             u16* __restrict__ xb) {
  int i = (blockIdx.x * 256 + threadIdx.x) * 4;
  float4 v = *(const float4*)(x + i);
  u16x4 o;
  o[0] = f2b(v.x); o[1] = f2b(v.y); o[2] = f2b(v.z); o[3] = f2b(v.w);
  *(u16x4*)(xb + i) = o;
}

// in [K][N] f32  ->  out [N][K] bf16   (transpose + convert)
__global__ __launch_bounds__(256) void wtrans(const float* __restrict__ in,
                                              u16* __restrict__ out,
                                              int N, int K) {
  __shared__ float tile[32][33];
  int tx = threadIdx.x & 31, ty = threadIdx.x >> 5;
  int n0 = blockIdx.x * 32, k0 = blockIdx.y * 32;
#pragma unroll
  for (int yy = 0; yy < 32; yy += 8)
    tile[ty + yy][tx] = in[(size_t)(k0 + ty + yy) * N + n0 + tx];
  __syncthreads();
#pragma unroll
  for (int yy = 0; yy < 32; yy += 8)
    out[(size_t)(n0 + ty + yy) * K + k0 + tx] = f2b(tile[tx][ty + yy]);
}

// RoPE in-place on q (cols 0..2047) and k (cols 2048..2559) of qkv [2048][3072]
__global__ __launch_bounds__(256) void rope_k(u16* __restrict__ qkv,
                                              const float* __restrict__ cs,
                                              const float* __restrict__ sn) {
  int idx = blockIdx.x * 256 + threadIdx.x;  // 2048*40*32
  int dp = idx & 31;
  int hh = (idx >> 5) % 40;
  int s  = idx / 1280;
  int col = (hh < 32) ? (hh * 64 + dp) : (2048 + (hh - 32) * 64 + dp);
  u16* p = qkv + (size_t)s * 3072 + col;
  float v1 = b2f(p[0]), v2 = b2f(p[32]);
  float c1 = cs[s * 64 + dp],      s1 = sn[s * 64 + dp];
  float c2 = cs[s * 64 + dp + 32], s2 = sn[s * 64 + dp + 32];
  p[0]  = f2b(v1 * c1 - v2 * s1);
  p[32] = f2b(v2 * c2 + v1 * s2);
}

// Vt[kh][d][s] = qkv[s][2560 + kh*64 + d]
__global__ __launch_bounds__(256) void vtrans(const u16* __restrict__ qkv,
                                              u16* __restrict__ Vt) {
  int idx = blockIdx.x * 256 + threadIdx.x;  // 8*64*2048 = 1<<20
  int s  = idx & 2047;
  int d  = (idx >> 11) & 63;
  int kh = idx >> 17;
  Vt[idx] = qkv[(size_t)s * 3072 + 2560 + kh * 64 + d];
}

// ---------------- GEMM: C[M][N] = A[M][K] * Bt[N][K]^T ----------------

__global__ __launch_bounds__(256) void gemm_bt(const u16* __restrict__ A,
                                               const u16* __restrict__ Bt,
                                               void* __restrict__ Cout,
                                               int M, int N, int K, int obf16) {
  __shared__ __align__(16) u16 As[128 * 32];
  __shared__ __align__(16) u16 Bs[128 * 32];
  const int t = threadIdx.x;
  const int lane = t & 63, wid = t >> 6;
  const int wm = (wid >> 1) * 64, wn = (wid & 1) * 64;
  const int la = lane & 15, lg = lane >> 4;
  const int m0 = blockIdx.y * 128, n0 = blockIdx.x * 128;

  const int c0 = wid * 2;
  const int srow = c0 * 16 + (lane >> 2);
  const int scol = (lane & 3) * 8;
  const u16* Ap = A + (size_t)(m0 + srow) * K + scol;
  const u16* Bp = Bt + (size_t)(n0 + srow) * K + scol;
  u16* Ad0 = &As[c0 * 512];
  u16* Ad1 = &As[(c0 + 1) * 512];
  u16* Bd0 = &Bs[c0 * 512];
  u16* Bd1 = &Bs[(c0 + 1) * 512];
  const size_t rstepA = (size_t)16 * K;

  f32x4 acc[4][4] = {};

  for (int k0 = 0; k0 < K; k0 += 32) {
    __syncthreads();
    gll16(Ap + k0, Ad0);
    gll16(Ap + k0 + rstepA, Ad1);
    gll16(Bp + k0, Bd0);
    gll16(Bp + k0 + rstepA, Bd1);
    __syncthreads();
    bf8 af[4], bfr[4];
#pragma unroll
    for (int i = 0; i < 4; ++i)
      af[i] = asbf8(*(const u16x8*)(&As[(wm + i * 16 + la) * 32 + lg * 8]));
#pragma unroll
    for (int j = 0; j < 4; ++j)
      bfr[j] = asbf8(*(const u16x8*)(&Bs[(wn + j * 16 + la) * 32 + lg * 8]));
    __builtin_amdgcn_s_setprio(1);
#pragma unroll
    for (int i = 0; i < 4; ++i)
#pragma unroll
      for (int j = 0; j < 4; ++j)
        acc[i][j] = __builtin_amdgcn_mfma_f32_16x16x32_bf16(af[i], bfr[j],
                                                            acc[i][j], 0, 0, 0);
    __builtin_amdgcn_s_setprio(0);
  }

#pragma unroll
  for (int i = 0; i < 4; ++i)
#pragma unroll
    for (int j = 0; j < 4; ++j)
#pragma unroll
      for (int r = 0; r < 4; ++r) {
        int row = m0 + wm + i * 16 + lg * 4 + r;
        int col = n0 + wn + j * 16 + la;
        if (obf16) ((u16*)Cout)[(size_t)row * N + col] = f2b(acc[i][j][r]);
        else       ((float*)Cout)[(size_t)row * N + col] = acc[i][j][r];
      }
}

// ---------------- flash attention: swapped-QK 32x32, kv-split x4 ----------
// Block = 256 threads = 4 waves for one (head, 32-row q-tile). Wave w owns a
// contiguous chunk of the kv-blocks with private (m,l,o); partials merged in
// LDS via log-sum-exp. S^T = mfma(K, Q) puts q lane-local: softmax fully
// in-register; P -> PV A-frags via cvt_pk + permlane32_swap (T12).

#define LOADKV(K0,K1,K2,K3,V0,V1,V2,V3,b) do {                       \
    const u16* kp_ = kbase + (size_t)(b) * 98304;                    \
    K0 = asbf8(*(const u16x8*)(kp_));                                \
    K1 = asbf8(*(const u16x8*)(kp_ + 16));                           \
    K2 = asbf8(*(const u16x8*)(kp_ + 32));                           \
    K3 = asbf8(*(const u16x8*)(kp_ + 48));                           \
    const u16* vp_ = vbase + (b) * 32;                               \
    V0 = asbf8(*(const u16x8*)(vp_));                                \
    V1 = asbf8(*(const u16x8*)(vp_ + 16));                           \
    V2 = asbf8(*(const u16x8*)(vp_ + 65536));                        \
    V3 = asbf8(*(const u16x8*)(vp_ + 65536 + 16));                   \
  } while (0)

#define STEP(K0,K1,K2,K3,V0,V1,V2,V3,b) do {                         \
    f32x16 s = {};                                                   \
    __builtin_amdgcn_s_setprio(1);                                   \
    s = __builtin_amdgcn_mfma_f32_32x32x16_bf16(K0, qf0, s, 0, 0, 0);\
    s = __builtin_amdgcn_mfma_f32_32x32x16_bf16(K1, qf1, s, 0, 0, 0);\
    s = __builtin_amdgcn_mfma_f32_32x32x16_bf16(K2, qf2, s, 0, 0, 0);\
    s = __builtin_amdgcn_mfma_f32_32x32x16_bf16(K3, qf3, s, 0, 0, 0);\
    __builtin_amdgcn_s_setprio(0);                                   \
    if ((b) == nb - 1) {                                             \
      _Pragma("unroll") for (int r = 0; r < 16; ++r) {               \
        int kvr = (b) * 32 + (r & 3) + 8 * (r >> 2) + 4 * hi;        \
        if (kvr > q0w + la) s[r] = -1e30f;                           \
      }                                                              \
    }                                                                \
    float pmax = s[0];                                               \
    _Pragma("unroll") for (int r = 1; r < 16; ++r)                   \
      pmax = fmaxf(pmax, s[r]);                                      \
    if (!__all(pmax - m_run <= 8.0f)) {                              \
      float om = __shfl_xor(pmax, 32);                               \
      float mn = fmaxf(m_run, fmaxf(pmax, om));                      \
      float sc = exp2f(m_run - mn);                                  \
      m_run = mn; l_run *= sc;                                       \
      _Pragma("unroll") for (int r = 0; r < 16; ++r) {               \
        float scr = __shfl(sc, (r & 3) + 8 * (r >> 2) + 4 * hi);     \
        o0[r] *= scr; o1[r] *= scr;                                  \
      }                                                              \
    }                                                                \
    float ls = 0.f;                                                  \
    _Pragma("unroll") for (int r = 0; r < 16; ++r) {                 \
      s[r] = exp2f(s[r] - m_run); ls += s[r];                        \
    }                                                                \
    l_run += ls;                                                     \
    u32 c0 = cvtpk(s[0], s[1]),   c1 = cvtpk(s[2], s[3]);            \
    u32 c2 = cvtpk(s[4], s[5]),   c3 = cvtpk(s[6], s[7]);            \
    u32 c4 = cvtpk(s[8], s[9]),   c5 = cvtpk(s[10], s[11]);          \
    u32 c6 = cvtpk(s[12], s[13]), c7 = cvtpk(s[14], s[15]);          \
    plswap(c0, c2); plswap(c1, c3); plswap(c4, c6); plswap(c5, c7);  \
    u32x4 t0; t0[0] = c0; t0[1] = c1; t0[2] = c2; t0[3] = c3;        \
    u32x4 t1; t1[0] = c4; t1[1] = c5; t1[2] = c6; t1[3] = c7;        \
    bf8 pa0 = __builtin_bit_cast(bf8, t0);                           \
    bf8 pa1 = __builtin_bit_cast(bf8, t1);                           \
    __builtin_amdgcn_s_setprio(1);                                   \
    o0 = __builtin_amdgcn_mfma_f32_32x32x16_bf16(pa0, V0, o0, 0, 0, 0);\
    o0 = __builtin_amdgcn_mfma_f32_32x32x16_bf16(pa1, V1, o0, 0, 0, 0);\
    o1 = __builtin_amdgcn_mfma_f32_32x32x16_bf16(pa0, V2, o1, 0, 0, 0);\
    o1 = __builtin_amdgcn_mfma_f32_32x32x16_bf16(pa1, V3, o1, 0, 0, 0);\
    __builtin_amdgcn_s_setprio(0);                                   \
  } while (0)

__global__ __launch_bounds__(256) void attn_fwd(const u16* __restrict__ qkv,
                                                const u16* __restrict__ Vt,
                                                u16* __restrict__ aout) {
  const int head = blockIdx.x;
  const int qt = 63 - (int)blockIdx.y;   // heavy q-tiles dispatch first
  const int nb = qt + 1;                 // 32-kv blocks total
  const int q0w = qt * 32;
  const int kh = head >> 2;              // GROUPS = 4
  const int t = threadIdx.x;
  const int w = t >> 6;                  // wave id = kv-chunk id
  const int lane = t & 63;
  const int la = lane & 31;
  const int hi = lane >> 5;

  __shared__ float mL[4][32];
  __shared__ float lL[4][32];
  __shared__ __align__(16) u16 oL[4][32][72];  // bf16 partial O, padded rows

  // kv-chunk partition: wave w gets [start, start+cnt)
  const int base = nb >> 2, rem = nb & 3;
  const int cnt = base + (w < rem);
  const int start = w * base + min(w, rem);

  // Q B-fragments, prescaled by 0.125*log2(e) (base-2 softmax domain)
  bf8 qf0, qf1, qf2, qf3;
  {
    const u16* qp = qkv + (size_t)(q0w + la) * 3072 + head * 64 + hi * 8;
    const float SC = 0.125f * 1.44269504088896340736f;
#define QLOAD(dst, kk) do {                                          \
      u16x8 v = *(const u16x8*)(qp + (kk) * 16);                     \
      u16x8 sv;                                                      \
      _Pragma("unroll") for (int e = 0; e < 8; ++e)                  \
        sv[e] = f2b(b2f(v[e]) * SC);                                 \
      dst = asbf8(sv);                                               \
    } while (0)
    QLOAD(qf0, 0); QLOAD(qf1, 1); QLOAD(qf2, 2); QLOAD(qf3, 3);
#undef QLOAD
  }

  const u16* kbase = qkv + (size_t)la * 3072 + 2048 + kh * 64 + hi * 8;
  const u16* vbase = Vt + ((size_t)kh * 64 + la) * 2048 + hi * 8;

  f32x16 o0 = {}, o1 = {};
  float m_run = -1e30f, l_run = 0.f;

  bf8 kA0, kA1, kA2, kA3, vA0, vA1, vA2, vA3;
  bf8 kB0, kB1, kB2, kB3, vB0, vB1, vB2, vB3;

  if (cnt > 0) {
    int b = start;
    const int e = start + cnt;
    LOADKV(kA0, kA1, kA2, kA3, vA0, vA1, vA2, vA3, b);
    for (;;) {
      if (b + 1 < e) LOADKV(kB0, kB1, kB2, kB3, vB0, vB1, vB2, vB3, b + 1);
      STEP(kA0, kA1, kA2, kA3, vA0, vA1, vA2, vA3, b);
      ++b; if (b >= e) break;
      if (b + 1 < e) LOADKV(kA0, kA1, kA2, kA3, vA0, vA1, vA2, vA3, b + 1);
      STEP(kB0, kB1, kB2, kB3, vB0, vB1, vB2, vB3, b);
      ++b; if (b >= e) break;
    }
  }

  // publish partials: m (per q=la, same in both halves), l (half-combined), O
  {
    float lt = l_run + __shfl_xor(l_run, 32);
    if (lane < 32) { mL[w][lane] = m_run; lL[w][lane] = lt; }
#pragma unroll
    for (int r = 0; r < 16; ++r) {
      int crow = (r & 3) + 8 * (r >> 2) + 4 * hi;
      oL[w][crow][la]      = f2b(o0[r]);
      oL[w][crow][la + 32] = f2b(o1[r]);
    }
  }
  __syncthreads();

  // log-sum-exp merge: thread t -> q = t>>3, d0 = (t&7)*8
  {
    const int q = t >> 3, d0 = (t & 7) * 8;
    float m0_ = mL[0][q], m1_ = mL[1][q], m2_ = mL[2][q], m3_ = mL[3][q];
    float mg = fmaxf(fmaxf(m0_, m1_), fmaxf(m2_, m3_));
    float s0 = exp2f(m0_ - mg), s1 = exp2f(m1_ - mg);
    float s2 = exp2f(m2_ - mg), s3 = exp2f(m3_ - mg);
    float lg = s0 * lL[0][q] + s1 * lL[1][q] + s2 * lL[2][q] + s3 * lL[3][q];
    float inv = 1.0f / lg;
    u16x8 p0 = *(const u16x8*)&oL[0][q][d0];
    u16x8 p1 = *(const u16x8*)&oL[1][q][d0];
    u16x8 p2 = *(const u16x8*)&oL[2][q][d0];
    u16x8 p3 = *(const u16x8*)&oL[3][q][d0];
    u16x8 outv;
#pragma unroll
    for (int j = 0; j < 8; ++j) {
      float sum = s0 * b2f(p0[j]) + s1 * b2f(p1[j]) +
                  s2 * b2f(p2[j]) + s3 * b2f(p3[j]);
      outv[j] = f2b(sum * inv);
    }
    *(u16x8*)(aout + (size_t)(q0w + q) * 2048 + head * 64 + d0) = outv;
  }
}

// ---------------- launch ----------------

extern "C" void kernel_launch(void* const* d_in, const int* in_sizes, int n_in,
                              void* d_out, int out_size, void* d_ws, size_t ws_size,
                              hipStream_t stream) {
  (void)in_sizes; (void)n_in; (void)out_size; (void)ws_size;
  const float* x  = (const float*)d_in[0];
  const float* wq = (const float*)d_in[1];
  const float* wk = (const float*)d_in[2];
  const float* wv = (const float*)d_in[3];
  const float* wo = (const float*)d_in[4];
  const float* cs = (const float*)d_in[5];
  const float* sn = (const float*)d_in[6];
  // d_in[7] = causal mask, implemented analytically

  u16* ws    = (u16*)d_ws;
  u16* xb    = ws;                               // [2048][2048]  (later reused as aout)
  u16* wqkvT = ws + 4194304;                     // [3072][2048]  (later reused for Vt)
  u16* qkv   = ws + 4194304 + 6291456;           // [2048][3072]
  u16* woT   = ws + 4194304 + 6291456 * 2;       // [2048][2048]
  u16* Vt    = wqkvT;                            // [8][64][2048] after G1 is done
  u16* aout  = xb;                               // after G1 is done

  xconv<<<4096, 256, 0, stream>>>(x, xb);
  wtrans<<<dim3(64, 64), 256, 0, stream>>>(wq, wqkvT, 2048, 2048);
  wtrans<<<dim3(16, 64), 256, 0, stream>>>(wk, wqkvT + (size_t)2048 * 2048, 512, 2048);
  wtrans<<<dim3(16, 64), 256, 0, stream>>>(wv, wqkvT + (size_t)2560 * 2048, 512, 2048);
  wtrans<<<dim3(64, 64), 256, 0, stream>>>(wo, woT, 2048, 2048);

  gemm_bt<<<dim3(24, 16), 256, 0, stream>>>(xb, wqkvT, qkv, 2048, 3072, 2048, 1);
  rope_k<<<10240, 256, 0, stream>>>(qkv, cs, sn);
  vtrans<<<4096, 256, 0, stream>>>(qkv, Vt);
  attn_fwd<<<dim3(32, 64), 256, 0, stream>>>(qkv, Vt, aout);
  gemm_bt<<<dim3(16, 16), 256, 0, stream>>>(aout, woT, d_out, 2048, 2048, 2048, 0);
}

// Round 6
// 201.291 us; speedup vs baseline: 1.1121x; 1.0811x over previous
//
#include <hip/hip_runtime.h>

typedef unsigned short u16;
typedef unsigned u32;
typedef u16 u16x8 __attribute__((ext_vector_type(8)));
typedef u16 u16x4 __attribute__((ext_vector_type(4)));
typedef u32 u32x4 __attribute__((ext_vector_type(4)));
typedef __bf16 bf8 __attribute__((ext_vector_type(8)));
typedef float f32x4 __attribute__((ext_vector_type(4)));
typedef float f32x16 __attribute__((ext_vector_type(16)));

__device__ __forceinline__ u16 f2b(float f) {
  unsigned u = __float_as_uint(f);
  u += 0x7FFFu + ((u >> 16) & 1u);   // RNE
  return (u16)(u >> 16);
}
__device__ __forceinline__ float b2f(u16 h) {
  return __uint_as_float(((unsigned)h) << 16);
}
__device__ __forceinline__ bf8 asbf8(u16x8 v) {
  return __builtin_bit_cast(bf8, v);
}
__device__ __forceinline__ void gll16(const u16* g, u16* l) {
  __builtin_amdgcn_global_load_lds(
      (const __attribute__((address_space(1))) unsigned*)(g),
      (__attribute__((address_space(3))) unsigned*)(l), 16, 0, 0);
}
__device__ __forceinline__ u32 cvtpk(float lo, float hi) {
  u32 r;
  asm("v_cvt_pk_bf16_f32 %0, %1, %2" : "=v"(r) : "v"(lo), "v"(hi));
  return r;
}
// v_permlane32_swap_b32 a, b:  a.hi32lanes <-> b.lo32lanes
// => a' = {lo: a.lo, hi: b.lo},  b' = {lo: a.hi, hi: b.hi}
__device__ __forceinline__ void plswap(u32& a, u32& b) {
  asm("v_permlane32_swap_b32 %0, %1" : "+v"(a), "+v"(b));
}

// ---------------- prep kernels ----------------

__global__ __launch_bounds__(256) void xconv(const float* __restrict__ x,
                                             u16* __restrict__ xb) {
  int i = (blockIdx.x * 256 + threadIdx.x) * 4;
  float4 v = *(const float4*)(x + i);
  u16x4 o;
  o[0] = f2b(v.x); o[1] = f2b(v.y); o[2] = f2b(v.z); o[3] = f2b(v.w);
  *(u16x4*)(xb + i) = o;
}

// in [K][N] f32  ->  out [N][K] bf16   (transpose + convert)
__global__ __launch_bounds__(256) void wtrans(const float* __restrict__ in,
                                              u16* __restrict__ out,
                                              int N, int K) {
  __shared__ float tile[32][33];
  int tx = threadIdx.x & 31, ty = threadIdx.x >> 5;
  int n0 = blockIdx.x * 32, k0 = blockIdx.y * 32;
#pragma unroll
  for (int yy = 0; yy < 32; yy += 8)
    tile[ty + yy][tx] = in[(size_t)(k0 + ty + yy) * N + n0 + tx];
  __syncthreads();
#pragma unroll
  for (int yy = 0; yy < 32; yy += 8)
    out[(size_t)(n0 + ty + yy) * K + k0 + tx] = f2b(tile[tx][ty + yy]);
}

// RoPE in-place on q (cols 0..2047) and k (cols 2048..2559) of qkv [2048][3072]
__global__ __launch_bounds__(256) void rope_k(u16* __restrict__ qkv,
                                              const float* __restrict__ cs,
                                              const float* __restrict__ sn) {
  int idx = blockIdx.x * 256 + threadIdx.x;  // 2048*40*32
  int dp = idx & 31;
  int hh = (idx >> 5) % 40;
  int s  = idx / 1280;
  int col = (hh < 32) ? (hh * 64 + dp) : (2048 + (hh - 32) * 64 + dp);
  u16* p = qkv + (size_t)s * 3072 + col;
  float v1 = b2f(p[0]), v2 = b2f(p[32]);
  float c1 = cs[s * 64 + dp],      s1 = sn[s * 64 + dp];
  float c2 = cs[s * 64 + dp + 32], s2 = sn[s * 64 + dp + 32];
  p[0]  = f2b(v1 * c1 - v2 * s1);
  p[32] = f2b(v2 * c2 + v1 * s2);
}

// K -> fragment-major Kf[kh][b][j][hi][la][8]:
//   Kf frag (kh,b,j) lane (hi*32+la) elem e = K[s=b*32+la][d=j*16+hi*8+e]
__global__ __launch_bounds__(256) void ktrans_f(const u16* __restrict__ qkv,
                                                u16* __restrict__ Kf) {
  int tid = blockIdx.x * 256 + threadIdx.x;   // 2048*64
  int s = tid >> 6, cc = tid & 63;
  int kh = cc >> 3, c = cc & 7;
  int j = c >> 1, hi = c & 1;
  int b = s >> 5, la = s & 31;
  u16x8 v = *(const u16x8*)(qkv + (size_t)s * 3072 + 2048 + cc * 8);
  *(u16x8*)(Kf + ((((size_t)(kh * 64 + b) * 4 + j) * 2 + hi) * 32 + la) * 8) = v;
}

// V -> fragment-major Vf[kh][b][f=m*2+jj][hi][la][8]:
//   Vf frag lane (hi*32+la) elem e = V[s=b*32+jj*16+hi*8+e][d=m*32+la]
__global__ __launch_bounds__(256) void vtrans_f(const u16* __restrict__ qkv,
                                                u16* __restrict__ Vf) {
  int tid = blockIdx.x * 256 + threadIdx.x;   // 2048*64
  int s = tid >> 6, cc = tid & 63;
  int kh = cc >> 3, c = cc & 7;
  int m = c >> 2, laB = (c & 3) * 8;
  int b = s >> 5, s5 = s & 31;
  int jj = s5 >> 4, hi = (s5 >> 3) & 1, e = s5 & 7;
  u16x8 v = *(const u16x8*)(qkv + (size_t)s * 3072 + 2560 + cc * 8);
  u16* dst = Vf + (((size_t)(kh * 64 + b) * 4 + m * 2 + jj) * 64 + hi * 32 + laB) * 8 + e;
#pragma unroll
  for (int i = 0; i < 8; ++i) dst[i * 8] = v[i];
}

// ---------------- GEMM: C[M][N] = A[M][K] * Bt[N][K]^T ----------------

__global__ __launch_bounds__(256) void gemm_bt(const u16* __restrict__ A,
                                               const u16* __restrict__ Bt,
                                               void* __restrict__ Cout,
                                               int M, int N, int K, int obf16) {
  __shared__ __align__(16) u16 As[128 * 32];
  __shared__ __align__(16) u16 Bs[128 * 32];
  const int t = threadIdx.x;
  const int lane = t & 63, wid = t >> 6;
  const int wm = (wid >> 1) * 64, wn = (wid & 1) * 64;
  const int la = lane & 15, lg = lane >> 4;
  const int m0 = blockIdx.y * 128, n0 = blockIdx.x * 128;

  const int c0 = wid * 2;
  const int srow = c0 * 16 + (lane >> 2);
  const int scol = (lane & 3) * 8;
  const u16* Ap = A + (size_t)(m0 + srow) * K + scol;
  const u16* Bp = Bt + (size_t)(n0 + srow) * K + scol;
  u16* Ad0 = &As[c0 * 512];
  u16* Ad1 = &As[(c0 + 1) * 512];
  u16* Bd0 = &Bs[c0 * 512];
  u16* Bd1 = &Bs[(c0 + 1) * 512];
  const size_t rstepA = (size_t)16 * K;

  f32x4 acc[4][4] = {};

  for (int k0 = 0; k0 < K; k0 += 32) {
    __syncthreads();
    gll16(Ap + k0, Ad0);
    gll16(Ap + k0 + rstepA, Ad1);
    gll16(Bp + k0, Bd0);
    gll16(Bp + k0 + rstepA, Bd1);
    __syncthreads();
    bf8 af[4], bfr[4];
#pragma unroll
    for (int i = 0; i < 4; ++i)
      af[i] = asbf8(*(const u16x8*)(&As[(wm + i * 16 + la) * 32 + lg * 8]));
#pragma unroll
    for (int j = 0; j < 4; ++j)
      bfr[j] = asbf8(*(const u16x8*)(&Bs[(wn + j * 16 + la) * 32 + lg * 8]));
    __builtin_amdgcn_s_setprio(1);
#pragma unroll
    for (int i = 0; i < 4; ++i)
#pragma unroll
      for (int j = 0; j < 4; ++j)
        acc[i][j] = __builtin_amdgcn_mfma_f32_16x16x32_bf16(af[i], bfr[j],
                                                            acc[i][j], 0, 0, 0);
    __builtin_amdgcn_s_setprio(0);
  }

#pragma unroll
  for (int i = 0; i < 4; ++i)
#pragma unroll
    for (int j = 0; j < 4; ++j)
#pragma unroll
      for (int r = 0; r < 4; ++r) {
        int row = m0 + wm + i * 16 + lg * 4 + r;
        int col = n0 + wn + j * 16 + la;
        if (obf16) ((u16*)Cout)[(size_t)row * N + col] = f2b(acc[i][j][r]);
        else       ((float*)Cout)[(size_t)row * N + col] = acc[i][j][r];
      }
}

// ---------------- flash attention: swapped-QK 32x32, kv-split x4 ----------
// Block = 256 threads = 4 waves for one (head, 32-row q-tile). Wave w owns a
// contiguous chunk of the kv-blocks with private (m,l,o); partials merged in
// LDS via log-sum-exp. K/V read from fragment-major Kf/Vf: every load is
// base + lane*16B, fully coalesced (1 line-burst vs 32 scattered lines).

#define LOADKV(K0,K1,K2,K3,V0,V1,V2,V3,b) do {                       \
    const u16* kp_ = kfb + (size_t)(b) * 2048;                       \
    K0 = asbf8(*(const u16x8*)(kp_));                                \
    K1 = asbf8(*(const u16x8*)(kp_ + 512));                          \
    K2 = asbf8(*(const u16x8*)(kp_ + 1024));                         \
    K3 = asbf8(*(const u16x8*)(kp_ + 1536));                         \
    const u16* vp_ = vfb + (size_t)(b) * 2048;                       \
    V0 = asbf8(*(const u16x8*)(vp_));                                \
    V1 = asbf8(*(const u16x8*)(vp_ + 512));                          \
    V2 = asbf8(*(const u16x8*)(vp_ + 1024));                         \
    V3 = asbf8(*(const u16x8*)(vp_ + 1536));                         \
  } while (0)

#define STEP(K0,K1,K2,K3,V0,V1,V2,V3,b) do {                         \
    f32x16 s = {};                                                   \
    __builtin_amdgcn_s_setprio(1);                                   \
    s = __builtin_amdgcn_mfma_f32_32x32x16_bf16(K0, qf0, s, 0, 0, 0);\
    s = __builtin_amdgcn_mfma_f32_32x32x16_bf16(K1, qf1, s, 0, 0, 0);\
    s = __builtin_amdgcn_mfma_f32_32x32x16_bf16(K2, qf2, s, 0, 0, 0);\
    s = __builtin_amdgcn_mfma_f32_32x32x16_bf16(K3, qf3, s, 0, 0, 0);\
    __builtin_amdgcn_s_setprio(0);                                   \
    if ((b) == nb - 1) {                                             \
      _Pragma("unroll") for (int r = 0; r < 16; ++r) {               \
        int kvr = (b) * 32 + (r & 3) + 8 * (r >> 2) + 4 * hi;        \
        if (kvr > q0w + la) s[r] = -1e30f;                           \
      }                                                              \
    }                                                                \
    float x0 = fmaxf(s[0], s[1]),   x1 = fmaxf(s[2], s[3]);          \
    float x2 = fmaxf(s[4], s[5]),   x3 = fmaxf(s[6], s[7]);          \
    float x4 = fmaxf(s[8], s[9]),   x5 = fmaxf(s[10], s[11]);        \
    float x6 = fmaxf(s[12], s[13]), x7 = fmaxf(s[14], s[15]);        \
    float y0 = fmaxf(x0, x1), y1 = fmaxf(x2, x3);                    \
    float y2 = fmaxf(x4, x5), y3 = fmaxf(x6, x7);                    \
    float pmax = fmaxf(fmaxf(y0, y1), fmaxf(y2, y3));                \
    if (!__all(pmax - m_run <= 8.0f)) {                              \
      float om = __shfl_xor(pmax, 32);                               \
      float mn = fmaxf(m_run, fmaxf(pmax, om));                      \
      float sc = exp2f(m_run - mn);                                  \
      m_run = mn; l_run *= sc;                                       \
      _Pragma("unroll") for (int r = 0; r < 16; ++r) {               \
        float scr = __shfl(sc, (r & 3) + 8 * (r >> 2) + 4 * hi);     \
        o0[r] *= scr; o1[r] *= scr;                                  \
      }                                                              \
    }                                                                \
    _Pragma("unroll") for (int r = 0; r < 16; ++r)                   \
      s[r] = exp2f(s[r] - m_run);                                    \
    float z0 = s[0] + s[1],   z1 = s[2] + s[3];                      \
    float z2 = s[4] + s[5],   z3 = s[6] + s[7];                      \
    float z4 = s[8] + s[9],   z5 = s[10] + s[11];                    \
    float z6 = s[12] + s[13], z7 = s[14] + s[15];                    \
    float w0 = z0 + z1, w1 = z2 + z3, w2 = z4 + z5, w3 = z6 + z7;    \
    l_run += (w0 + w1) + (w2 + w3);                                  \
    u32 c0 = cvtpk(s[0], s[1]),   c1 = cvtpk(s[2], s[3]);            \
    u32 c2 = cvtpk(s[4], s[5]),   c3 = cvtpk(s[6], s[7]);            \
    u32 c4 = cvtpk(s[8], s[9]),   c5 = cvtpk(s[10], s[11]);          \
    u32 c6 = cvtpk(s[12], s[13]), c7 = cvtpk(s[14], s[15]);          \
    plswap(c0, c2); plswap(c1, c3); plswap(c4, c6); plswap(c5, c7);  \
    u32x4 t0; t0[0] = c0; t0[1] = c1; t0[2] = c2; t0[3] = c3;        \
    u32x4 t1; t1[0] = c4; t1[1] = c5; t1[2] = c6; t1[3] = c7;        \
    bf8 pa0 = __builtin_bit_cast(bf8, t0);                           \
    bf8 pa1 = __builtin_bit_cast(bf8, t1);                           \
    __builtin_amdgcn_s_setprio(1);                                   \
    o0 = __builtin_amdgcn_mfma_f32_32x32x16_bf16(pa0, V0, o0, 0, 0, 0);\
    o0 = __builtin_amdgcn_mfma_f32_32x32x16_bf16(pa1, V1, o0, 0, 0, 0);\
    o1 = __builtin_amdgcn_mfma_f32_32x32x16_bf16(pa0, V2, o1, 0, 0, 0);\
    o1 = __builtin_amdgcn_mfma_f32_32x32x16_bf16(pa1, V3, o1, 0, 0, 0);\
    __builtin_amdgcn_s_setprio(0);                                   \
  } while (0)

__global__ __launch_bounds__(256) void attn_fwd(const u16* __restrict__ qkv,
                                                const u16* __restrict__ Kf,
                                                const u16* __restrict__ Vf,
                                                u16* __restrict__ aout) {
  const int head = blockIdx.x;
  const int qt = 63 - (int)blockIdx.y;   // heavy q-tiles dispatch first
  const int nb = qt + 1;                 // 32-kv blocks total
  const int q0w = qt * 32;
  const int kh = head >> 2;              // GROUPS = 4
  const int t = threadIdx.x;
  const int w = t >> 6;                  // wave id = kv-chunk id
  const int lane = t & 63;
  const int la = lane & 31;
  const int hi = lane >> 5;

  __shared__ float mL[4][32];
  __shared__ float lL[4][32];
  __shared__ __align__(16) u16 oL[4][32][72];  // bf16 partial O, padded rows

  // kv-chunk partition: wave w gets [start, start+cnt)
  const int base = nb >> 2, rem = nb & 3;
  const int cnt = base + (w < rem);
  const int start = w * base + min(w, rem);

  // Q B-fragments, prescaled by 0.125*log2(e) (base-2 softmax domain)
  bf8 qf0, qf1, qf2, qf3;
  {
    const u16* qp = qkv + (size_t)(q0w + la) * 3072 + head * 64 + hi * 8;
    const float SC = 0.125f * 1.44269504088896340736f;
#define QLOAD(dst, kk) do {                                          \
      u16x8 v = *(const u16x8*)(qp + (kk) * 16);                     \
      u16x8 sv;                                                      \
      _Pragma("unroll") for (int e = 0; e < 8; ++e)                  \
        sv[e] = f2b(b2f(v[e]) * SC);                                 \
      dst = asbf8(sv);                                               \
    } while (0)
    QLOAD(qf0, 0); QLOAD(qf1, 1); QLOAD(qf2, 2); QLOAD(qf3, 3);
#undef QLOAD
  }

  const u16* kfb = Kf + (size_t)kh * 131072 + (size_t)lane * 8;
  const u16* vfb = Vf + (size_t)kh * 131072 + (size_t)lane * 8;

  f32x16 o0 = {}, o1 = {};
  float m_run = -1e30f, l_run = 0.f;

  bf8 kA0, kA1, kA2, kA3, vA0, vA1, vA2, vA3;
  bf8 kB0, kB1, kB2, kB3, vB0, vB1, vB2, vB3;

  if (cnt > 0) {
    int b = start;
    const int e = start + cnt;
    LOADKV(kA0, kA1, kA2, kA3, vA0, vA1, vA2, vA3, b);
    for (;;) {
      if (b + 1 < e) LOADKV(kB0, kB1, kB2, kB3, vB0, vB1, vB2, vB3, b + 1);
      STEP(kA0, kA1, kA2, kA3, vA0, vA1, vA2, vA3, b);
      ++b; if (b >= e) break;
      if (b + 1 < e) LOADKV(kA0, kA1, kA2, kA3, vA0, vA1, vA2, vA3, b + 1);
      STEP(kB0, kB1, kB2, kB3, vB0, vB1, vB2, vB3, b);
      ++b; if (b >= e) break;
    }
  }

  // publish partials: m (per q=la, same in both halves), l (half-combined), O
  {
    float lt = l_run + __shfl_xor(l_run, 32);
    if (lane < 32) { mL[w][lane] = m_run; lL[w][lane] = lt; }
#pragma unroll
    for (int r = 0; r < 16; ++r) {
      int crow = (r & 3) + 8 * (r >> 2) + 4 * hi;
      oL[w][crow][la]      = f2b(o0[r]);
      oL[w][crow][la + 32] = f2b(o1[r]);
    }
  }
  __syncthreads();

  // log-sum-exp merge: thread t -> q = t>>3, d0 = (t&7)*8
  {
    const int q = t >> 3, d0 = (t & 7) * 8;
    float m0_ = mL[0][q], m1_ = mL[1][q], m2_ = mL[2][q], m3_ = mL[3][q];
    float mg = fmaxf(fmaxf(m0_, m1_), fmaxf(m2_, m3_));
    float s0 = exp2f(m0_ - mg), s1 = exp2f(m1_ - mg);
    float s2 = exp2f(m2_ - mg), s3 = exp2f(m3_ - mg);
    float lg = s0 * lL[0][q] + s1 * lL[1][q] + s2 * lL[2][q] + s3 * lL[3][q];
    float inv = 1.0f / lg;
    u16x8 p0 = *(const u16x8*)&oL[0][q][d0];
    u16x8 p1 = *(const u16x8*)&oL[1][q][d0];
    u16x8 p2 = *(const u16x8*)&oL[2][q][d0];
    u16x8 p3 = *(const u16x8*)&oL[3][q][d0];
    u16x8 outv;
#pragma unroll
    for (int j = 0; j < 8; ++j) {
      float sum = s0 * b2f(p0[j]) + s1 * b2f(p1[j]) +
                  s2 * b2f(p2[j]) + s3 * b2f(p3[j]);
      outv[j] = f2b(sum * inv);
    }
    *(u16x8*)(aout + (size_t)(q0w + q) * 2048 + head * 64 + d0) = outv;
  }
}

// ---------------- launch ----------------

extern "C" void kernel_launch(void* const* d_in, const int* in_sizes, int n_in,
                              void* d_out, int out_size, void* d_ws, size_t ws_size,
                              hipStream_t stream) {
  (void)in_sizes; (void)n_in; (void)out_size; (void)ws_size;
  const float* x  = (const float*)d_in[0];
  const float* wq = (const float*)d_in[1];
  const float* wk = (const float*)d_in[2];
  const float* wv = (const float*)d_in[3];
  const float* wo = (const float*)d_in[4];
  const float* cs = (const float*)d_in[5];
  const float* sn = (const float*)d_in[6];
  // d_in[7] = causal mask, implemented analytically

  u16* ws    = (u16*)d_ws;
  u16* xb    = ws;                               // [2048][2048]  (later reused as aout)
  u16* wqkvT = ws + 4194304;                     // [3072][2048]  (later reused for Kf/Vf)
  u16* qkv   = ws + 4194304 + 6291456;           // [2048][3072]
  u16* woT   = ws + 4194304 + 6291456 * 2;       // [2048][2048]
  u16* Kf    = wqkvT;                            // [8][64][4][2][32][8] after G1
  u16* Vf    = wqkvT + 1048576;                  // [8][64][4][2][32][8] after G1
  u16* aout  = xb;                               // after G1 is done

  xconv<<<4096, 256, 0, stream>>>(x, xb);
  wtrans<<<dim3(64, 64), 256, 0, stream>>>(wq, wqkvT, 2048, 2048);
  wtrans<<<dim3(16, 64), 256, 0, stream>>>(wk, wqkvT + (size_t)2048 * 2048, 512, 2048);
  wtrans<<<dim3(16, 64), 256, 0, stream>>>(wv, wqkvT + (size_t)2560 * 2048, 512, 2048);
  wtrans<<<dim3(64, 64), 256, 0, stream>>>(wo, woT, 2048, 2048);

  gemm_bt<<<dim3(24, 16), 256, 0, stream>>>(xb, wqkvT, qkv, 2048, 3072, 2048, 1);
  rope_k<<<10240, 256, 0, stream>>>(qkv, cs, sn);
  ktrans_f<<<512, 256, 0, stream>>>(qkv, Kf);
  vtrans_f<<<512, 256, 0, stream>>>(qkv, Vf);
  attn_fwd<<<dim3(32, 64), 256, 0, stream>>>(qkv, Kf, Vf, aout);
  gemm_bt<<<dim3(16, 16), 256, 0, stream>>>(aout, woT, d_out, 2048, 2048, 2048, 0);
}

// Round 7
// 163.420 us; speedup vs baseline: 1.3698x; 1.2317x over previous
//
#include <hip/hip_runtime.h>

typedef unsigned short u16;
typedef unsigned u32;
typedef u16 u16x8 __attribute__((ext_vector_type(8)));
typedef u16 u16x4 __attribute__((ext_vector_type(4)));
typedef u32 u32x4 __attribute__((ext_vector_type(4)));
typedef __bf16 bf8 __attribute__((ext_vector_type(8)));
typedef float f32x4 __attribute__((ext_vector_type(4)));
typedef float f32x16 __attribute__((ext_vector_type(16)));

__device__ __forceinline__ u16 f2b(float f) {
  unsigned u = __float_as_uint(f);
  u += 0x7FFFu + ((u >> 16) & 1u);   // RNE
  return (u16)(u >> 16);
}
__device__ __forceinline__ float b2f(u16 h) {
  return __uint_as_float(((unsigned)h) << 16);
}
__device__ __forceinline__ bf8 asbf8(u16x8 v) {
  return __builtin_bit_cast(bf8, v);
}
__device__ __forceinline__ void gll16(const u16* g, u16* l) {
  __builtin_amdgcn_global_load_lds(
      (const __attribute__((address_space(1))) unsigned*)(g),
      (__attribute__((address_space(3))) unsigned*)(l), 16, 0, 0);
}
__device__ __forceinline__ u32 cvtpk(float lo, float hi) {
  u32 r;
  asm("v_cvt_pk_bf16_f32 %0, %1, %2" : "=v"(r) : "v"(lo), "v"(hi));
  return r;
}
// v_permlane32_swap_b32 a, b:  a.hi32lanes <-> b.lo32lanes
__device__ __forceinline__ void plswap(u32& a, u32& b) {
  asm("v_permlane32_swap_b32 %0, %1" : "+v"(a), "+v"(b));
}

// ---------------- prep kernels ----------------

__global__ __launch_bounds__(256) void xconv(const float* __restrict__ x,
                                             u16* __restrict__ xb) {
  int i = (blockIdx.x * 256 + threadIdx.x) * 4;
  float4 v = *(const float4*)(x + i);
  u16x4 o;
  o[0] = f2b(v.x); o[1] = f2b(v.y); o[2] = f2b(v.z); o[3] = f2b(v.w);
  *(u16x4*)(xb + i) = o;
}

// in [K][N] f32  ->  out [N][K] bf16   (transpose + convert)
__global__ __launch_bounds__(256) void wtrans(const float* __restrict__ in,
                                              u16* __restrict__ out,
                                              int N, int K) {
  __shared__ float tile[32][33];
  int tx = threadIdx.x & 31, ty = threadIdx.x >> 5;
  int n0 = blockIdx.x * 32, k0 = blockIdx.y * 32;
#pragma unroll
  for (int yy = 0; yy < 32; yy += 8)
    tile[ty + yy][tx] = in[(size_t)(k0 + ty + yy) * N + n0 + tx];
  __syncthreads();
#pragma unroll
  for (int yy = 0; yy < 32; yy += 8)
    out[(size_t)(n0 + ty + yy) * K + k0 + tx] = f2b(tile[tx][ty + yy]);
}

// split-K reduce for qkv + fused RoPE. p0 (=qkv region) updated in place.
__global__ __launch_bounds__(256) void reduce_qkv(u16* __restrict__ p0,
                                                  const u16* __restrict__ p1,
                                                  const float* __restrict__ cs,
                                                  const float* __restrict__ sn) {
  int idx = blockIdx.x * 256 + threadIdx.x;      // 2048*384
  int s = idx / 384, c8 = (idx % 384) * 8;
  size_t base = (size_t)s * 3072 + c8;
  if (c8 < 2560) {                               // q or k head: RoPE pairs
    int hc = c8 & 63;
    if (hc >= 32) return;                        // partner handles
    u16x8 a0 = *(const u16x8*)(p0 + base);
    u16x8 a1 = *(const u16x8*)(p1 + base);
    u16x8 b0 = *(const u16x8*)(p0 + base + 32);
    u16x8 b1 = *(const u16x8*)(p1 + base + 32);
    u16x8 oa, ob;
#pragma unroll
    for (int e = 0; e < 8; ++e) {
      float va = b2f(a0[e]) + b2f(a1[e]);
      float vb = b2f(b0[e]) + b2f(b1[e]);
      float c1 = cs[s * 64 + hc + e],      s1 = sn[s * 64 + hc + e];
      float c2 = cs[s * 64 + hc + 32 + e], s2 = sn[s * 64 + hc + 32 + e];
      oa[e] = f2b(va * c1 - vb * s1);
      ob[e] = f2b(vb * c2 + va * s2);
    }
    *(u16x8*)(p0 + base)      = oa;
    *(u16x8*)(p0 + base + 32) = ob;
  } else {                                       // v: plain sum
    u16x8 a0 = *(const u16x8*)(p0 + base);
    u16x8 a1 = *(const u16x8*)(p1 + base);
    u16x8 o;
#pragma unroll
    for (int e = 0; e < 8; ++e) o[e] = f2b(b2f(a0[e]) + b2f(a1[e]));
    *(u16x8*)(p0 + base) = o;
  }
}

// split-K reduce for out-proj -> f32 d_out
__global__ __launch_bounds__(256) void reduce_out(const u16* __restrict__ p0,
                                                  const u16* __restrict__ p1,
                                                  float* __restrict__ out) {
  int idx = blockIdx.x * 256 + threadIdx.x;      // 2048*256
  size_t base = (size_t)idx * 8;
  u16x8 a0 = *(const u16x8*)(p0 + base);
  u16x8 a1 = *(const u16x8*)(p1 + base);
  float4 lo, hi;
  lo.x = b2f(a0[0]) + b2f(a1[0]); lo.y = b2f(a0[1]) + b2f(a1[1]);
  lo.z = b2f(a0[2]) + b2f(a1[2]); lo.w = b2f(a0[3]) + b2f(a1[3]);
  hi.x = b2f(a0[4]) + b2f(a1[4]); hi.y = b2f(a0[5]) + b2f(a1[5]);
  hi.z = b2f(a0[6]) + b2f(a1[6]); hi.w = b2f(a0[7]) + b2f(a1[7]);
  *(float4*)(out + base)     = lo;
  *(float4*)(out + base + 4) = hi;
}

// K -> fragment-major Kf[kh][b][j][hi][la][8]
__global__ __launch_bounds__(256) void ktrans_f(const u16* __restrict__ qkv,
                                                u16* __restrict__ Kf) {
  int tid = blockIdx.x * 256 + threadIdx.x;   // 2048*64
  int s = tid >> 6, cc = tid & 63;
  int kh = cc >> 3, c = cc & 7;
  int j = c >> 1, hi = c & 1;
  int b = s >> 5, la = s & 31;
  u16x8 v = *(const u16x8*)(qkv + (size_t)s * 3072 + 2048 + cc * 8);
  *(u16x8*)(Kf + ((((size_t)(kh * 64 + b) * 4 + j) * 2 + hi) * 32 + la) * 8) = v;
}

// V -> fragment-major Vf[kh][b][f=m*2+jj][hi][la][8]
__global__ __launch_bounds__(256) void vtrans_f(const u16* __restrict__ qkv,
                                                u16* __restrict__ Vf) {
  int tid = blockIdx.x * 256 + threadIdx.x;   // 2048*64
  int s = tid >> 6, cc = tid & 63;
  int kh = cc >> 3, c = cc & 7;
  int m = c >> 2, laB = (c & 3) * 8;
  int b = s >> 5, s5 = s & 31;
  int jj = s5 >> 4, hi = (s5 >> 3) & 1, e = s5 & 7;
  u16x8 v = *(const u16x8*)(qkv + (size_t)s * 3072 + 2560 + cc * 8);
  u16* dst = Vf + (((size_t)(kh * 64 + b) * 4 + m * 2 + jj) * 64 + hi * 32 + laB) * 8 + e;
#pragma unroll
  for (int i = 0; i < 8; ++i) dst[i * 8] = v[i];
}

// ------- split-K GEMM: Cz[M][N] (bf16) = A[M][kbeg:kbeg+KH] * Bt^T --------
// m97 structure per block; blockIdx.z selects K-half and partial buffer.

__global__ __launch_bounds__(256) void gemm_sk(const u16* __restrict__ A,
                                               const u16* __restrict__ Bt,
                                               u16* __restrict__ C0,
                                               u16* __restrict__ C1,
                                               int N, int Kfull, int KH) {
  __shared__ __align__(16) u16 As[128 * 32];
  __shared__ __align__(16) u16 Bs[128 * 32];
  const int t = threadIdx.x;
  const int lane = t & 63, wid = t >> 6;
  const int wm = (wid >> 1) * 64, wn = (wid & 1) * 64;
  const int la = lane & 15, lg = lane >> 4;
  const int m0 = blockIdx.y * 128, n0 = blockIdx.x * 128;
  const int kbeg = blockIdx.z * KH;
  u16* C = blockIdx.z ? C1 : C0;

  const int c0 = wid * 2;
  const int srow = c0 * 16 + (lane >> 2);
  const int scol = (lane & 3) * 8;
  const u16* Ap = A + (size_t)(m0 + srow) * Kfull + kbeg + scol;
  const u16* Bp = Bt + (size_t)(n0 + srow) * Kfull + kbeg + scol;
  u16* Ad0 = &As[c0 * 512];
  u16* Ad1 = &As[(c0 + 1) * 512];
  u16* Bd0 = &Bs[c0 * 512];
  u16* Bd1 = &Bs[(c0 + 1) * 512];
  const size_t rstep = (size_t)16 * Kfull;

  f32x4 acc[4][4] = {};

  for (int k0 = 0; k0 < KH; k0 += 32) {
    __syncthreads();
    gll16(Ap + k0, Ad0);
    gll16(Ap + k0 + rstep, Ad1);
    gll16(Bp + k0, Bd0);
    gll16(Bp + k0 + rstep, Bd1);
    __syncthreads();
    bf8 af[4], bfr[4];
#pragma unroll
    for (int i = 0; i < 4; ++i)
      af[i] = asbf8(*(const u16x8*)(&As[(wm + i * 16 + la) * 32 + lg * 8]));
#pragma unroll
    for (int j = 0; j < 4; ++j)
      bfr[j] = asbf8(*(const u16x8*)(&Bs[(wn + j * 16 + la) * 32 + lg * 8]));
    __builtin_amdgcn_s_setprio(1);
#pragma unroll
    for (int i = 0; i < 4; ++i)
#pragma unroll
      for (int j = 0; j < 4; ++j)
        acc[i][j] = __builtin_amdgcn_mfma_f32_16x16x32_bf16(af[i], bfr[j],
                                                            acc[i][j], 0, 0, 0);
    __builtin_amdgcn_s_setprio(0);
  }

#pragma unroll
  for (int i = 0; i < 4; ++i)
#pragma unroll
    for (int j = 0; j < 4; ++j)
#pragma unroll
      for (int r = 0; r < 4; ++r) {
        int row = m0 + wm + i * 16 + lg * 4 + r;
        int col = n0 + wn + j * 16 + la;
        C[(size_t)row * N + col] = f2b(acc[i][j][r]);
      }
}

// ---------------- flash attention: swapped-QK 32x32, kv-split x4 ----------

#define LOADKV(K0,K1,K2,K3,V0,V1,V2,V3,b) do {                       \
    const u16* kp_ = kfb + (size_t)(b) * 2048;                       \
    K0 = asbf8(*(const u16x8*)(kp_));                                \
    K1 = asbf8(*(const u16x8*)(kp_ + 512));                          \
    K2 = asbf8(*(const u16x8*)(kp_ + 1024));                         \
    K3 = asbf8(*(const u16x8*)(kp_ + 1536));                         \
    const u16* vp_ = vfb + (size_t)(b) * 2048;                       \
    V0 = asbf8(*(const u16x8*)(vp_));                                \
    V1 = asbf8(*(const u16x8*)(vp_ + 512));                          \
    V2 = asbf8(*(const u16x8*)(vp_ + 1024));                         \
    V3 = asbf8(*(const u16x8*)(vp_ + 1536));                         \
  } while (0)

#define STEP(K0,K1,K2,K3,V0,V1,V2,V3,b) do {                         \
    f32x16 s = {};                                                   \
    __builtin_amdgcn_s_setprio(1);                                   \
    s = __builtin_amdgcn_mfma_f32_32x32x16_bf16(K0, qf0, s, 0, 0, 0);\
    s = __builtin_amdgcn_mfma_f32_32x32x16_bf16(K1, qf1, s, 0, 0, 0);\
    s = __builtin_amdgcn_mfma_f32_32x32x16_bf16(K2, qf2, s, 0, 0, 0);\
    s = __builtin_amdgcn_mfma_f32_32x32x16_bf16(K3, qf3, s, 0, 0, 0);\
    __builtin_amdgcn_s_setprio(0);                                   \
    if ((b) == nb - 1) {                                             \
      _Pragma("unroll") for (int r = 0; r < 16; ++r) {               \
        int kvr = (b) * 32 + (r & 3) + 8 * (r >> 2) + 4 * hi;        \
        if (kvr > q0w + la) s[r] = -1e30f;                           \
      }                                                              \
    }                                                                \
    float x0 = fmaxf(s[0], s[1]),   x1 = fmaxf(s[2], s[3]);          \
    float x2 = fmaxf(s[4], s[5]),   x3 = fmaxf(s[6], s[7]);          \
    float x4 = fmaxf(s[8], s[9]),   x5 = fmaxf(s[10], s[11]);        \
    float x6 = fmaxf(s[12], s[13]), x7 = fmaxf(s[14], s[15]);        \
    float y0 = fmaxf(x0, x1), y1 = fmaxf(x2, x3);                    \
    float y2 = fmaxf(x4, x5), y3 = fmaxf(x6, x7);                    \
    float pmax = fmaxf(fmaxf(y0, y1), fmaxf(y2, y3));                \
    if (!__all(pmax - m_run <= 8.0f)) {                              \
      float om = __shfl_xor(pmax, 32);                               \
      float mn = fmaxf(m_run, fmaxf(pmax, om));                      \
      float sc = exp2f(m_run - mn);                                  \
      m_run = mn; l_run *= sc;                                       \
      _Pragma("unroll") for (int r = 0; r < 16; ++r) {               \
        float scr = __shfl(sc, (r & 3) + 8 * (r >> 2) + 4 * hi);     \
        o0[r] *= scr; o1[r] *= scr;                                  \
      }                                                              \
    }                                                                \
    _Pragma("unroll") for (int r = 0; r < 16; ++r)                   \
      s[r] = exp2f(s[r] - m_run);                                    \
    float z0 = s[0] + s[1],   z1 = s[2] + s[3];                      \
    float z2 = s[4] + s[5],   z3 = s[6] + s[7];                      \
    float z4 = s[8] + s[9],   z5 = s[10] + s[11];                    \
    float z6 = s[12] + s[13], z7 = s[14] + s[15];                    \
    float w0 = z0 + z1, w1 = z2 + z3, w2 = z4 + z5, w3 = z6 + z7;    \
    l_run += (w0 + w1) + (w2 + w3);                                  \
    u32 c0 = cvtpk(s[0], s[1]),   c1 = cvtpk(s[2], s[3]);            \
    u32 c2 = cvtpk(s[4], s[5]),   c3 = cvtpk(s[6], s[7]);            \
    u32 c4 = cvtpk(s[8], s[9]),   c5 = cvtpk(s[10], s[11]);          \
    u32 c6 = cvtpk(s[12], s[13]), c7 = cvtpk(s[14], s[15]);          \
    plswap(c0, c2); plswap(c1, c3); plswap(c4, c6); plswap(c5, c7);  \
    u32x4 t0; t0[0] = c0; t0[1] = c1; t0[2] = c2; t0[3] = c3;        \
    u32x4 t1; t1[0] = c4; t1[1] = c5; t1[2] = c6; t1[3] = c7;        \
    bf8 pa0 = __builtin_bit_cast(bf8, t0);                           \
    bf8 pa1 = __builtin_bit_cast(bf8, t1);                           \
    __builtin_amdgcn_s_setprio(1);                                   \
    o0 = __builtin_amdgcn_mfma_f32_32x32x16_bf16(pa0, V0, o0, 0, 0, 0);\
    o0 = __builtin_amdgcn_mfma_f32_32x32x16_bf16(pa1, V1, o0, 0, 0, 0);\
    o1 = __builtin_amdgcn_mfma_f32_32x32x16_bf16(pa0, V2, o1, 0, 0, 0);\
    o1 = __builtin_amdgcn_mfma_f32_32x32x16_bf16(pa1, V3, o1, 0, 0, 0);\
    __builtin_amdgcn_s_setprio(0);                                   \
  } while (0)

__global__ __launch_bounds__(256) void attn_fwd(const u16* __restrict__ qkv,
                                                const u16* __restrict__ Kf,
                                                const u16* __restrict__ Vf,
                                                u16* __restrict__ aout) {
  const int head = blockIdx.x;
  const int qt = 63 - (int)blockIdx.y;   // heavy q-tiles dispatch first
  const int nb = qt + 1;                 // 32-kv blocks total
  const int q0w = qt * 32;
  const int kh = head >> 2;              // GROUPS = 4
  const int t = threadIdx.x;
  const int w = t >> 6;                  // wave id = kv-chunk id
  const int lane = t & 63;
  const int la = lane & 31;
  const int hi = lane >> 5;

  __shared__ float mL[4][32];
  __shared__ float lL[4][32];
  __shared__ __align__(16) u16 oL[4][32][72];

  const int base = nb >> 2, rem = nb & 3;
  const int cnt = base + (w < rem);
  const int start = w * base + min(w, rem);

  bf8 qf0, qf1, qf2, qf3;
  {
    const u16* qp = qkv + (size_t)(q0w + la) * 3072 + head * 64 + hi * 8;
    const float SC = 0.125f * 1.44269504088896340736f;
#define QLOAD(dst, kk) do {                                          \
      u16x8 v = *(const u16x8*)(qp + (kk) * 16);                     \
      u16x8 sv;                                                      \
      _Pragma("unroll") for (int e = 0; e < 8; ++e)                  \
        sv[e] = f2b(b2f(v[e]) * SC);                                 \
      dst = asbf8(sv);                                               \
    } while (0)
    QLOAD(qf0, 0); QLOAD(qf1, 1); QLOAD(qf2, 2); QLOAD(qf3, 3);
#undef QLOAD
  }

  const u16* kfb = Kf + (size_t)kh * 131072 + (size_t)lane * 8;
  const u16* vfb = Vf + (size_t)kh * 131072 + (size_t)lane * 8;

  f32x16 o0 = {}, o1 = {};
  float m_run = -1e30f, l_run = 0.f;

  bf8 kA0, kA1, kA2, kA3, vA0, vA1, vA2, vA3;
  bf8 kB0, kB1, kB2, kB3, vB0, vB1, vB2, vB3;

  if (cnt > 0) {
    int b = start;
    const int e = start + cnt;
    LOADKV(kA0, kA1, kA2, kA3, vA0, vA1, vA2, vA3, b);
    for (;;) {
      if (b + 1 < e) LOADKV(kB0, kB1, kB2, kB3, vB0, vB1, vB2, vB3, b + 1);
      STEP(kA0, kA1, kA2, kA3, vA0, vA1, vA2, vA3, b);
      ++b; if (b >= e) break;
      if (b + 1 < e) LOADKV(kA0, kA1, kA2, kA3, vA0, vA1, vA2, vA3, b + 1);
      STEP(kB0, kB1, kB2, kB3, vB0, vB1, vB2, vB3, b);
      ++b; if (b >= e) break;
    }
  }

  {
    float lt = l_run + __shfl_xor(l_run, 32);
    if (lane < 32) { mL[w][lane] = m_run; lL[w][lane] = lt; }
#pragma unroll
    for (int r = 0; r < 16; ++r) {
      int crow = (r & 3) + 8 * (r >> 2) + 4 * hi;
      oL[w][crow][la]      = f2b(o0[r]);
      oL[w][crow][la + 32] = f2b(o1[r]);
    }
  }
  __syncthreads();

  {
    const int q = t >> 3, d0 = (t & 7) * 8;
    float m0_ = mL[0][q], m1_ = mL[1][q], m2_ = mL[2][q], m3_ = mL[3][q];
    float mg = fmaxf(fmaxf(m0_, m1_), fmaxf(m2_, m3_));
    float s0 = exp2f(m0_ - mg), s1 = exp2f(m1_ - mg);
    float s2 = exp2f(m2_ - mg), s3 = exp2f(m3_ - mg);
    float lg = s0 * lL[0][q] + s1 * lL[1][q] + s2 * lL[2][q] + s3 * lL[3][q];
    float inv = 1.0f / lg;
    u16x8 p0 = *(const u16x8*)&oL[0][q][d0];
    u16x8 p1 = *(const u16x8*)&oL[1][q][d0];
    u16x8 p2 = *(const u16x8*)&oL[2][q][d0];
    u16x8 p3 = *(const u16x8*)&oL[3][q][d0];
    u16x8 outv;
#pragma unroll
    for (int j = 0; j < 8; ++j) {
      float sum = s0 * b2f(p0[j]) + s1 * b2f(p1[j]) +
                  s2 * b2f(p2[j]) + s3 * b2f(p3[j]);
      outv[j] = f2b(sum * inv);
    }
    *(u16x8*)(aout + (size_t)(q0w + q) * 2048 + head * 64 + d0) = outv;
  }
}

// ---------------- launch ----------------

extern "C" void kernel_launch(void* const* d_in, const int* in_sizes, int n_in,
                              void* d_out, int out_size, void* d_ws, size_t ws_size,
                              hipStream_t stream) {
  (void)in_sizes; (void)n_in; (void)out_size; (void)ws_size;
  const float* x  = (const float*)d_in[0];
  const float* wq = (const float*)d_in[1];
  const float* wk = (const float*)d_in[2];
  const float* wv = (const float*)d_in[3];
  const float* wo = (const float*)d_in[4];
  const float* cs = (const float*)d_in[5];
  const float* sn = (const float*)d_in[6];
  // d_in[7] = causal mask, implemented analytically

  u16* ws    = (u16*)d_ws;
  u16* xb    = ws;                         // [2048][2048] bf16 (later aout)
  u16* wqkvT = ws + 4194304;               // [3072][2048] bf16 (later Kf/Vf)
  u16* qkv   = ws + 10485760;              // [2048][3072] bf16; QKV partial z=0 in place
  u16* woT   = ws + 16777216;              // [2048][2048] bf16
  u16* ext   = ws + 20971520;              // [2048][3072] bf16: QKV partial z=1
  u16* Kf    = wqkvT;                      // [8][64][4][2][32][8] after QKV gemm
  u16* Vf    = wqkvT + 1048576;
  u16* aout  = xb;
  u16* op0   = qkv;                        // out-proj partials (qkv region free)
  u16* op1   = ext;

  xconv<<<4096, 256, 0, stream>>>(x, xb);
  wtrans<<<dim3(64, 64), 256, 0, stream>>>(wq, wqkvT, 2048, 2048);
  wtrans<<<dim3(16, 64), 256, 0, stream>>>(wk, wqkvT + (size_t)2048 * 2048, 512, 2048);
  wtrans<<<dim3(16, 64), 256, 0, stream>>>(wv, wqkvT + (size_t)2560 * 2048, 512, 2048);
  wtrans<<<dim3(64, 64), 256, 0, stream>>>(wo, woT, 2048, 2048);

  // QKV: [2048][3072], split-K x2 (768 blocks)
  gemm_sk<<<dim3(24, 16, 2), 256, 0, stream>>>(xb, wqkvT, qkv, ext, 3072, 2048, 1024);
  reduce_qkv<<<3072, 256, 0, stream>>>(qkv, ext, cs, sn);
  ktrans_f<<<512, 256, 0, stream>>>(qkv, Kf);
  vtrans_f<<<512, 256, 0, stream>>>(qkv, Vf);
  attn_fwd<<<dim3(32, 64), 256, 0, stream>>>(qkv, Kf, Vf, aout);
  // out-proj: [2048][2048], split-K x2 (512 blocks)
  gemm_sk<<<dim3(16, 16, 2), 256, 0, stream>>>(aout, woT, op0, op1, 2048, 2048, 1024);
  reduce_out<<<2048, 256, 0, stream>>>(op0, op1, (float*)d_out);
}

// Round 8
// 155.545 us; speedup vs baseline: 1.4391x; 1.0506x over previous
//
#include <hip/hip_runtime.h>

typedef unsigned short u16;
typedef unsigned u32;
typedef u16 u16x8 __attribute__((ext_vector_type(8)));
typedef u16 u16x4 __attribute__((ext_vector_type(4)));
typedef u32 u32x4 __attribute__((ext_vector_type(4)));
typedef __bf16 bf8 __attribute__((ext_vector_type(8)));
typedef float f32x4 __attribute__((ext_vector_type(4)));
typedef float f32x16 __attribute__((ext_vector_type(16)));

__device__ __forceinline__ u16 f2b(float f) {
  unsigned u = __float_as_uint(f);
  u += 0x7FFFu + ((u >> 16) & 1u);   // RNE
  return (u16)(u >> 16);
}
__device__ __forceinline__ float b2f(u16 h) {
  return __uint_as_float(((unsigned)h) << 16);
}
__device__ __forceinline__ bf8 asbf8(u16x8 v) {
  return __builtin_bit_cast(bf8, v);
}
__device__ __forceinline__ void gll16(const u16* g, u16* l) {
  __builtin_amdgcn_global_load_lds(
      (const __attribute__((address_space(1))) unsigned*)(g),
      (__attribute__((address_space(3))) unsigned*)(l), 16, 0, 0);
}
__device__ __forceinline__ u32 cvtpk(float lo, float hi) {
  u32 r;
  asm("v_cvt_pk_bf16_f32 %0, %1, %2" : "=v"(r) : "v"(lo), "v"(hi));
  return r;
}
// v_permlane32_swap_b32 a, b:  a.hi32lanes <-> b.lo32lanes
__device__ __forceinline__ void plswap(u32& a, u32& b) {
  asm("v_permlane32_swap_b32 %0, %1" : "+v"(a), "+v"(b));
}
__device__ __forceinline__ float max3f(float a, float b, float c) {
  float r;
  asm("v_max3_f32 %0, %1, %2, %3" : "=v"(r) : "v"(a), "v"(b), "v"(c));
  return r;
}
__device__ __forceinline__ float ex2(float x) {
  return __builtin_amdgcn_exp2f(x);
}

// ---------------- prep kernels ----------------

__global__ __launch_bounds__(256) void xconv(const float* __restrict__ x,
                                             u16* __restrict__ xb) {
  int i = (blockIdx.x * 256 + threadIdx.x) * 4;
  float4 v = *(const float4*)(x + i);
  u16x4 o;
  o[0] = f2b(v.x); o[1] = f2b(v.y); o[2] = f2b(v.z); o[3] = f2b(v.w);
  *(u16x4*)(xb + i) = o;
}

// in [K][N] f32  ->  out [N][K] bf16   (transpose + convert)
__global__ __launch_bounds__(256) void wtrans(const float* __restrict__ in,
                                              u16* __restrict__ out,
                                              int N, int K) {
  __shared__ float tile[32][33];
  int tx = threadIdx.x & 31, ty = threadIdx.x >> 5;
  int n0 = blockIdx.x * 32, k0 = blockIdx.y * 32;
#pragma unroll
  for (int yy = 0; yy < 32; yy += 8)
    tile[ty + yy][tx] = in[(size_t)(k0 + ty + yy) * N + n0 + tx];
  __syncthreads();
#pragma unroll
  for (int yy = 0; yy < 32; yy += 8)
    out[(size_t)(n0 + ty + yy) * K + k0 + tx] = f2b(tile[tx][ty + yy]);
}

// split-K reduce for qkv + fused RoPE. p0 (=qkv region) updated in place.
__global__ __launch_bounds__(256) void reduce_qkv(u16* __restrict__ p0,
                                                  const u16* __restrict__ p1,
                                                  const float* __restrict__ cs,
                                                  const float* __restrict__ sn) {
  int idx = blockIdx.x * 256 + threadIdx.x;      // 2048*384
  int s = idx / 384, c8 = (idx % 384) * 8;
  size_t base = (size_t)s * 3072 + c8;
  if (c8 < 2560) {                               // q or k head: RoPE pairs
    int hc = c8 & 63;
    if (hc >= 32) return;                        // partner handles
    u16x8 a0 = *(const u16x8*)(p0 + base);
    u16x8 a1 = *(const u16x8*)(p1 + base);
    u16x8 b0 = *(const u16x8*)(p0 + base + 32);
    u16x8 b1 = *(const u16x8*)(p1 + base + 32);
    u16x8 oa, ob;
#pragma unroll
    for (int e = 0; e < 8; ++e) {
      float va = b2f(a0[e]) + b2f(a1[e]);
      float vb = b2f(b0[e]) + b2f(b1[e]);
      float c1 = cs[s * 64 + hc + e],      s1 = sn[s * 64 + hc + e];
      float c2 = cs[s * 64 + hc + 32 + e], s2 = sn[s * 64 + hc + 32 + e];
      oa[e] = f2b(va * c1 - vb * s1);
      ob[e] = f2b(vb * c2 + va * s2);
    }
    *(u16x8*)(p0 + base)      = oa;
    *(u16x8*)(p0 + base + 32) = ob;
  } else {                                       // v: plain sum
    u16x8 a0 = *(const u16x8*)(p0 + base);
    u16x8 a1 = *(const u16x8*)(p1 + base);
    u16x8 o;
#pragma unroll
    for (int e = 0; e < 8; ++e) o[e] = f2b(b2f(a0[e]) + b2f(a1[e]));
    *(u16x8*)(p0 + base) = o;
  }
}

// split-K reduce for out-proj -> f32 d_out
__global__ __launch_bounds__(256) void reduce_out(const u16* __restrict__ p0,
                                                  const u16* __restrict__ p1,
                                                  float* __restrict__ out) {
  int idx = blockIdx.x * 256 + threadIdx.x;      // 2048*256
  size_t base = (size_t)idx * 8;
  u16x8 a0 = *(const u16x8*)(p0 + base);
  u16x8 a1 = *(const u16x8*)(p1 + base);
  float4 lo, hi;
  lo.x = b2f(a0[0]) + b2f(a1[0]); lo.y = b2f(a0[1]) + b2f(a1[1]);
  lo.z = b2f(a0[2]) + b2f(a1[2]); lo.w = b2f(a0[3]) + b2f(a1[3]);
  hi.x = b2f(a0[4]) + b2f(a1[4]); hi.y = b2f(a0[5]) + b2f(a1[5]);
  hi.z = b2f(a0[6]) + b2f(a1[6]); hi.w = b2f(a0[7]) + b2f(a1[7]);
  *(float4*)(out + base)     = lo;
  *(float4*)(out + base + 4) = hi;
}

// K -> fragment-major Kf[kh][b][j][hi][la][8]
__global__ __launch_bounds__(256) void ktrans_f(const u16* __restrict__ qkv,
                                                u16* __restrict__ Kf) {
  int tid = blockIdx.x * 256 + threadIdx.x;   // 2048*64
  int s = tid >> 6, cc = tid & 63;
  int kh = cc >> 3, c = cc & 7;
  int j = c >> 1, hi = c & 1;
  int b = s >> 5, la = s & 31;
  u16x8 v = *(const u16x8*)(qkv + (size_t)s * 3072 + 2048 + cc * 8);
  *(u16x8*)(Kf + ((((size_t)(kh * 64 + b) * 4 + j) * 2 + hi) * 32 + la) * 8) = v;
}

// V -> fragment-major Vf[kh][b][f=m*2+jj][hi][la][8]
__global__ __launch_bounds__(256) void vtrans_f(const u16* __restrict__ qkv,
                                                u16* __restrict__ Vf) {
  int tid = blockIdx.x * 256 + threadIdx.x;   // 2048*64
  int s = tid >> 6, cc = tid & 63;
  int kh = cc >> 3, c = cc & 7;
  int m = c >> 2, laB = (c & 3) * 8;
  int b = s >> 5, s5 = s & 31;
  int jj = s5 >> 4, hi = (s5 >> 3) & 1, e = s5 & 7;
  u16x8 v = *(const u16x8*)(qkv + (size_t)s * 3072 + 2560 + cc * 8);
  u16* dst = Vf + (((size_t)(kh * 64 + b) * 4 + m * 2 + jj) * 64 + hi * 32 + laB) * 8 + e;
#pragma unroll
  for (int i = 0; i < 8; ++i) dst[i * 8] = v[i];
}

// ------- split-K GEMM: Cz[M][N] (bf16) = A[M][kbeg:kbeg+KH] * Bt^T --------

__global__ __launch_bounds__(256) void gemm_sk(const u16* __restrict__ A,
                                               const u16* __restrict__ Bt,
                                               u16* __restrict__ C0,
                                               u16* __restrict__ C1,
                                               int N, int Kfull, int KH) {
  __shared__ __align__(16) u16 As[128 * 32];
  __shared__ __align__(16) u16 Bs[128 * 32];
  const int t = threadIdx.x;
  const int lane = t & 63, wid = t >> 6;
  const int wm = (wid >> 1) * 64, wn = (wid & 1) * 64;
  const int la = lane & 15, lg = lane >> 4;
  const int m0 = blockIdx.y * 128, n0 = blockIdx.x * 128;
  const int kbeg = blockIdx.z * KH;
  u16* C = blockIdx.z ? C1 : C0;

  const int c0 = wid * 2;
  const int srow = c0 * 16 + (lane >> 2);
  const int scol = (lane & 3) * 8;
  const u16* Ap = A + (size_t)(m0 + srow) * Kfull + kbeg + scol;
  const u16* Bp = Bt + (size_t)(n0 + srow) * Kfull + kbeg + scol;
  u16* Ad0 = &As[c0 * 512];
  u16* Ad1 = &As[(c0 + 1) * 512];
  u16* Bd0 = &Bs[c0 * 512];
  u16* Bd1 = &Bs[(c0 + 1) * 512];
  const size_t rstep = (size_t)16 * Kfull;

  f32x4 acc[4][4] = {};

  for (int k0 = 0; k0 < KH; k0 += 32) {
    __syncthreads();
    gll16(Ap + k0, Ad0);
    gll16(Ap + k0 + rstep, Ad1);
    gll16(Bp + k0, Bd0);
    gll16(Bp + k0 + rstep, Bd1);
    __syncthreads();
    bf8 af[4], bfr[4];
#pragma unroll
    for (int i = 0; i < 4; ++i)
      af[i] = asbf8(*(const u16x8*)(&As[(wm + i * 16 + la) * 32 + lg * 8]));
#pragma unroll
    for (int j = 0; j < 4; ++j)
      bfr[j] = asbf8(*(const u16x8*)(&Bs[(wn + j * 16 + la) * 32 + lg * 8]));
    __builtin_amdgcn_s_setprio(1);
#pragma unroll
    for (int i = 0; i < 4; ++i)
#pragma unroll
      for (int j = 0; j < 4; ++j)
        acc[i][j] = __builtin_amdgcn_mfma_f32_16x16x32_bf16(af[i], bfr[j],
                                                            acc[i][j], 0, 0, 0);
    __builtin_amdgcn_s_setprio(0);
  }

#pragma unroll
  for (int i = 0; i < 4; ++i)
#pragma unroll
    for (int j = 0; j < 4; ++j)
#pragma unroll
      for (int r = 0; r < 4; ++r) {
        int row = m0 + wm + i * 16 + lg * 4 + r;
        int col = n0 + wn + j * 16 + la;
        C[(size_t)row * N + col] = f2b(acc[i][j][r]);
      }
}

// ---------------- flash attention: swapped-QK 32x32, kv-split x4 ----------

#define LOADKV(K0,K1,K2,K3,V0,V1,V2,V3,b) do {                       \
    const u16* kp_ = kfb + (size_t)(b) * 2048;                       \
    K0 = asbf8(*(const u16x8*)(kp_));                                \
    K1 = asbf8(*(const u16x8*)(kp_ + 512));                          \
    K2 = asbf8(*(const u16x8*)(kp_ + 1024));                         \
    K3 = asbf8(*(const u16x8*)(kp_ + 1536));                         \
    const u16* vp_ = vfb + (size_t)(b) * 2048;                       \
    V0 = asbf8(*(const u16x8*)(vp_));                                \
    V1 = asbf8(*(const u16x8*)(vp_ + 512));                          \
    V2 = asbf8(*(const u16x8*)(vp_ + 1024));                         \
    V3 = asbf8(*(const u16x8*)(vp_ + 1536));                         \
  } while (0)

// common: QK^T, causal mask, tree-max -> s, pmax
#define QKMAX(K0,K1,K2,K3,b) \
    f32x16 s = {};                                                   \
    __builtin_amdgcn_s_setprio(1);                                   \
    s = __builtin_amdgcn_mfma_f32_32x32x16_bf16(K0, qf0, s, 0, 0, 0);\
    s = __builtin_amdgcn_mfma_f32_32x32x16_bf16(K1, qf1, s, 0, 0, 0);\
    s = __builtin_amdgcn_mfma_f32_32x32x16_bf16(K2, qf2, s, 0, 0, 0);\
    s = __builtin_amdgcn_mfma_f32_32x32x16_bf16(K3, qf3, s, 0, 0, 0);\
    __builtin_amdgcn_s_setprio(0);                                   \
    if ((b) == nb - 1) {                                             \
      _Pragma("unroll") for (int r = 0; r < 16; ++r) {               \
        int kvr = (b) * 32 + (r & 3) + 8 * (r >> 2) + 4 * hi;        \
        if (kvr > q0w + la) s[r] = -1e30f;                           \
      }                                                              \
    }                                                                \
    float pmax = fmaxf(                                              \
        max3f(max3f(s[0], s[1], s[2]),  max3f(s[3], s[4], s[5]),     \
              max3f(s[6], s[7], s[8])),                              \
        max3f(max3f(s[9], s[10], s[11]),                             \
              max3f(s[12], s[13], s[14]), s[15]));

// common tail: exp2, row-sum, pack, PV
#define EXPPV(V0,V1,V2,V3) do {                                      \
    _Pragma("unroll") for (int r = 0; r < 16; ++r)                   \
      s[r] = ex2(s[r] - m_run);                                      \
    float z0 = s[0] + s[1],   z1 = s[2] + s[3];                      \
    float z2 = s[4] + s[5],   z3 = s[6] + s[7];                      \
    float z4 = s[8] + s[9],   z5 = s[10] + s[11];                    \
    float z6 = s[12] + s[13], z7 = s[14] + s[15];                    \
    float w0 = z0 + z1, w1 = z2 + z3, w2 = z4 + z5, w3 = z6 + z7;    \
    l_run += (w0 + w1) + (w2 + w3);                                  \
    u32 c0 = cvtpk(s[0], s[1]),   c1 = cvtpk(s[2], s[3]);            \
    u32 c2 = cvtpk(s[4], s[5]),   c3 = cvtpk(s[6], s[7]);            \
    u32 c4 = cvtpk(s[8], s[9]),   c5 = cvtpk(s[10], s[11]);          \
    u32 c6 = cvtpk(s[12], s[13]), c7 = cvtpk(s[14], s[15]);          \
    plswap(c0, c2); plswap(c1, c3); plswap(c4, c6); plswap(c5, c7);  \
    u32x4 t0; t0[0] = c0; t0[1] = c1; t0[2] = c2; t0[3] = c3;        \
    u32x4 t1; t1[0] = c4; t1[1] = c5; t1[2] = c6; t1[3] = c7;        \
    bf8 pa0 = __builtin_bit_cast(bf8, t0);                           \
    bf8 pa1 = __builtin_bit_cast(bf8, t1);                           \
    __builtin_amdgcn_s_setprio(1);                                   \
    o0 = __builtin_amdgcn_mfma_f32_32x32x16_bf16(pa0, V0, o0, 0, 0, 0);\
    o0 = __builtin_amdgcn_mfma_f32_32x32x16_bf16(pa1, V1, o0, 0, 0, 0);\
    o1 = __builtin_amdgcn_mfma_f32_32x32x16_bf16(pa0, V2, o1, 0, 0, 0);\
    o1 = __builtin_amdgcn_mfma_f32_32x32x16_bf16(pa1, V3, o1, 0, 0, 0);\
    __builtin_amdgcn_s_setprio(0);                                   \
  } while (0)

// first step of a chunk: set m_run directly, no rescale path
#define STEP1(K0,K1,K2,K3,V0,V1,V2,V3,b) do {                        \
    QKMAX(K0,K1,K2,K3,b)                                             \
    float om = __shfl_xor(pmax, 32);                                 \
    m_run = fmaxf(pmax, om);                                         \
    EXPPV(V0,V1,V2,V3);                                              \
  } while (0)

// steady step: defer-max (T13, THR=8)
#define STEP(K0,K1,K2,K3,V0,V1,V2,V3,b) do {                         \
    QKMAX(K0,K1,K2,K3,b)                                             \
    if (!__all(pmax - m_run <= 8.0f)) {                              \
      float om = __shfl_xor(pmax, 32);                               \
      float mn = fmaxf(m_run, fmaxf(pmax, om));                      \
      float sc = ex2(m_run - mn);                                    \
      m_run = mn; l_run *= sc;                                       \
      _Pragma("unroll") for (int r = 0; r < 16; ++r) {               \
        float scr = __shfl(sc, (r & 3) + 8 * (r >> 2) + 4 * hi);     \
        o0[r] *= scr; o1[r] *= scr;                                  \
      }                                                              \
    }                                                                \
    EXPPV(V0,V1,V2,V3);                                              \
  } while (0)

__global__ __launch_bounds__(256) void attn_fwd(const u16* __restrict__ qkv,
                                                const u16* __restrict__ Kf,
                                                const u16* __restrict__ Vf,
                                                u16* __restrict__ aout) {
  const int head = blockIdx.x;
  const int qt = 63 - (int)blockIdx.y;   // heavy q-tiles dispatch first
  const int nb = qt + 1;                 // 32-kv blocks total
  const int q0w = qt * 32;
  const int kh = head >> 2;              // GROUPS = 4
  const int t = threadIdx.x;
  const int w = t >> 6;                  // wave id = kv-chunk id
  const int lane = t & 63;
  const int la = lane & 31;
  const int hi = lane >> 5;

  __shared__ float mL[4][32];
  __shared__ float lL[4][32];
  __shared__ __align__(16) u16 oL[4][32][72];

  const int base = nb >> 2, rem = nb & 3;
  const int cnt = base + (w < rem);
  const int start = w * base + min(w, rem);

  bf8 qf0, qf1, qf2, qf3;
  {
    const u16* qp = qkv + (size_t)(q0w + la) * 3072 + head * 64 + hi * 8;
    const float SC = 0.125f * 1.44269504088896340736f;
#define QLOAD(dst, kk) do {                                          \
      u16x8 v = *(const u16x8*)(qp + (kk) * 16);                     \
      u16x8 sv;                                                      \
      _Pragma("unroll") for (int e = 0; e < 8; ++e)                  \
        sv[e] = f2b(b2f(v[e]) * SC);                                 \
      dst = asbf8(sv);                                               \
    } while (0)
    QLOAD(qf0, 0); QLOAD(qf1, 1); QLOAD(qf2, 2); QLOAD(qf3, 3);
#undef QLOAD
  }

  const u16* kfb = Kf + (size_t)kh * 131072 + (size_t)lane * 8;
  const u16* vfb = Vf + (size_t)kh * 131072 + (size_t)lane * 8;

  f32x16 o0 = {}, o1 = {};
  float m_run = -1e30f, l_run = 0.f;

  bf8 kA0, kA1, kA2, kA3, vA0, vA1, vA2, vA3;
  bf8 kB0, kB1, kB2, kB3, vB0, vB1, vB2, vB3;

  if (cnt > 0) {
    int b = start;
    const int e = start + cnt;
    LOADKV(kA0, kA1, kA2, kA3, vA0, vA1, vA2, vA3, b);
    if (b + 1 < e) LOADKV(kB0, kB1, kB2, kB3, vB0, vB1, vB2, vB3, b + 1);
    STEP1(kA0, kA1, kA2, kA3, vA0, vA1, vA2, vA3, b);
    ++b;
    while (b < e) {
      if (b + 1 < e) LOADKV(kA0, kA1, kA2, kA3, vA0, vA1, vA2, vA3, b + 1);
      STEP(kB0, kB1, kB2, kB3, vB0, vB1, vB2, vB3, b);
      ++b; if (b >= e) break;
      if (b + 1 < e) LOADKV(kB0, kB1, kB2, kB3, vB0, vB1, vB2, vB3, b + 1);
      STEP(kA0, kA1, kA2, kA3, vA0, vA1, vA2, vA3, b);
      ++b;
    }
  }

  {
    float lt = l_run + __shfl_xor(l_run, 32);
    if (lane < 32) { mL[w][lane] = m_run; lL[w][lane] = lt; }
#pragma unroll
    for (int r = 0; r < 16; ++r) {
      int crow = (r & 3) + 8 * (r >> 2) + 4 * hi;
      oL[w][crow][la]      = f2b(o0[r]);
      oL[w][crow][la + 32] = f2b(o1[r]);
    }
  }
  __syncthreads();

  {
    const int q = t >> 3, d0 = (t & 7) * 8;
    float m0_ = mL[0][q], m1_ = mL[1][q], m2_ = mL[2][q], m3_ = mL[3][q];
    float mg = fmaxf(fmaxf(m0_, m1_), fmaxf(m2_, m3_));
    float s0 = ex2(m0_ - mg), s1 = ex2(m1_ - mg);
    float s2 = ex2(m2_ - mg), s3 = ex2(m3_ - mg);
    float lg = s0 * lL[0][q] + s1 * lL[1][q] + s2 * lL[2][q] + s3 * lL[3][q];
    float inv = 1.0f / lg;
    u16x8 p0 = *(const u16x8*)&oL[0][q][d0];
    u16x8 p1 = *(const u16x8*)&oL[1][q][d0];
    u16x8 p2 = *(const u16x8*)&oL[2][q][d0];
    u16x8 p3 = *(const u16x8*)&oL[3][q][d0];
    u16x8 outv;
#pragma unroll
    for (int j = 0; j < 8; ++j) {
      float sum = s0 * b2f(p0[j]) + s1 * b2f(p1[j]) +
                  s2 * b2f(p2[j]) + s3 * b2f(p3[j]);
      outv[j] = f2b(sum * inv);
    }
    *(u16x8*)(aout + (size_t)(q0w + q) * 2048 + head * 64 + d0) = outv;
  }
}

// ---------------- launch ----------------

extern "C" void kernel_launch(void* const* d_in, const int* in_sizes, int n_in,
                              void* d_out, int out_size, void* d_ws, size_t ws_size,
                              hipStream_t stream) {
  (void)in_sizes; (void)n_in; (void)out_size; (void)ws_size;
  const float* x  = (const float*)d_in[0];
  const float* wq = (const float*)d_in[1];
  const float* wk = (const float*)d_in[2];
  const float* wv = (const float*)d_in[3];
  const float* wo = (const float*)d_in[4];
  const float* cs = (const float*)d_in[5];
  const float* sn = (const float*)d_in[6];
  // d_in[7] = causal mask, implemented analytically

  u16* ws    = (u16*)d_ws;
  u16* xb    = ws;                         // [2048][2048] bf16 (later aout)
  u16* wqkvT = ws + 4194304;               // [3072][2048] bf16 (later Kf/Vf)
  u16* qkv   = ws + 10485760;              // [2048][3072] bf16; QKV partial z=0 in place
  u16* woT   = ws + 16777216;              // [2048][2048] bf16
  u16* ext   = ws + 20971520;              // [2048][3072] bf16: QKV partial z=1
  u16* Kf    = wqkvT;                      // [8][64][4][2][32][8] after QKV gemm
  u16* Vf    = wqkvT + 1048576;
  u16* aout  = xb;
  u16* op0   = qkv;                        // out-proj partials (qkv region free)
  u16* op1   = ext;

  xconv<<<4096, 256, 0, stream>>>(x, xb);
  wtrans<<<dim3(64, 64), 256, 0, stream>>>(wq, wqkvT, 2048, 2048);
  wtrans<<<dim3(16, 64), 256, 0, stream>>>(wk, wqkvT + (size_t)2048 * 2048, 512, 2048);
  wtrans<<<dim3(16, 64), 256, 0, stream>>>(wv, wqkvT + (size_t)2560 * 2048, 512, 2048);
  wtrans<<<dim3(64, 64), 256, 0, stream>>>(wo, woT, 2048, 2048);

  // QKV: [2048][3072], split-K x2 (768 blocks)
  gemm_sk<<<dim3(24, 16, 2), 256, 0, stream>>>(xb, wqkvT, qkv, ext, 3072, 2048, 1024);
  reduce_qkv<<<3072, 256, 0, stream>>>(qkv, ext, cs, sn);
  ktrans_f<<<512, 256, 0, stream>>>(qkv, Kf);
  vtrans_f<<<512, 256, 0, stream>>>(qkv, Vf);
  attn_fwd<<<dim3(32, 64), 256, 0, stream>>>(qkv, Kf, Vf, aout);
  // out-proj: [2048][2048], split-K x2 (512 blocks)
  gemm_sk<<<dim3(16, 16, 2), 256, 0, stream>>>(aout, woT, op0, op1, 2048, 2048, 1024);
  reduce_out<<<2048, 256, 0, stream>>>(op0, op1, (float*)d_out);
}